// Round 8
// baseline (1079.713 us; speedup 1.0000x reference)
//
#include <hip/hip_runtime.h>
#include <math.h>

#define B_ 32
#define N_ 128
#define E_ 16384
#define EPS_ 1e-5f

typedef short short8v __attribute__((ext_vector_type(8)));
typedef float f32x4v __attribute__((ext_vector_type(4)));

// ---- ws layout (float offsets): IDENTICAL to round-0 proven layout ----
#define WS_STATS_E 0        // 144 accs, stride 16 floats (line-padded)
#define WS_STATS_H 2304
#define WS_MAGG    4608     // B*N*72  (doubles as P_mid before k_edge2v3)
#define WS_AGG     299520   // B*N*4
#define WS_CNT     315904   // B*N
#define WS_ZERO_END 320000
#define WS_AE      320000
#define WS_BE      320072
#define WS_AH      320144
#define WS_BH      320216
#define WS_WX1T    320288   // 72*72 transposed
#define WS_ZH1     325472   // B*N*72  (doubles as P_top before k_node1; canary scratch first)
// total = 620384 floats == round-0 proven footprint

#define HOUT_OFF 0
#define XOUT_OFF 294912
#define M_OFF    311296

static __device__ __forceinline__ short f2bf(float f) {
    unsigned int u = __builtin_bit_cast(unsigned int, f);
    u += 0x7FFFu + ((u >> 16) & 1u);
    return (short)(u >> 16);
}

// -------------------- MFMA canary: 1 block, 1 wave, output overwritten later ----------
__global__ void k_canary(const float* __restrict__ src, float* __restrict__ dst) {
    __shared__ short As[16 * 32];
    __shared__ short Bs[16 * 32];
    int l = threadIdx.x;                 // 64 threads
    for (int idx = l; idx < 512; idx += 64) {
        As[idx] = f2bf(src[idx]);
        Bs[idx] = f2bf(src[512 + idx]);
    }
    __syncthreads();
    int ln = l & 15, g4 = l >> 4;
    short8v a = *(const short8v*)&As[ln * 32 + g4 * 8];
    short8v b = *(const short8v*)&Bs[ln * 32 + g4 * 8];
    f32x4v acc = {0.f, 0.f, 0.f, 0.f};
    acc = __builtin_amdgcn_mfma_f32_16x16x32_bf16(a, b, acc, 0, 0, 0);
#pragma unroll
    for (int r = 0; r < 4; ++r) dst[(g4 * 4 + r) * 16 + ln] = acc[r];
}

// -------------------- small prep: transpose W_x1 (round-0 verbatim) --------------------
__global__ void k_transpose(const float* __restrict__ Wx1, float* __restrict__ WT) {
    int idx = blockIdx.x * 256 + threadIdx.x;
    if (idx < 72 * 72) {
        int r = idx / 72, c = idx - r * 72;
        WT[c * 72 + r] = Wx1[idx];
    }
}

// ---- node projections: P_top = h@We1[0:72], P_mid = h@We1[72:144], c-quartered ----
__global__ __launch_bounds__(256) void k_nodeproj(
    const float* __restrict__ h, const float* __restrict__ We1,
    float* __restrict__ Ptop, float* __restrict__ Pmid)
{
    int gid = blockIdx.x * 256 + threadIdx.x;    // < 32768
    int which = gid >> 14;                        // 0: top, 1: mid
    int rem = gid & 16383;
    int row = rem >> 2;                           // 4096 rows
    int q = rem & 3;                              // c-quarter
    int c0 = q * 18;
    const float4* h4 = (const float4*)(h + (size_t)row * 72);
    const float* base = We1 + which * 5184 + c0;
    float acc[18];
#pragma unroll
    for (int c = 0; c < 18; ++c) acc[c] = 0.f;
    for (int kc = 0; kc < 18; ++kc) {
        float4 a = h4[kc];
        const float* wr = base + (kc * 4) * 72;
#pragma unroll
        for (int c = 0; c < 18; ++c)
            acc[c] = fmaf(a.x, wr[c], fmaf(a.y, wr[72 + c], fmaf(a.z, wr[144 + c], fmaf(a.w, wr[216 + c], acc[c]))));
    }
    float* P = (which ? Pmid : Ptop) + (size_t)row * 72 + c0;
#pragma unroll
    for (int c = 0; c < 18; ++c) P[c] = acc[c];
}

// -------------------- edge pass 1: z1 = Pt[i]+Pm[j]+norms*w144+dots*w145 (+BN stats) ----
__global__ __launch_bounds__(256) void k_edge1v2(
    const float* __restrict__ x,
    const int* __restrict__ ei, const int* __restrict__ ej,
    const float* __restrict__ Ptop, const float* __restrict__ Pmid,
    const float* __restrict__ We1,
    float* __restrict__ z1, float* __restrict__ gstats)
{
    __shared__ float ls[144 * 33];
    int t = threadIdx.x;
    for (int idx = t; idx < 144 * 33; idx += 256) ls[idx] = 0.f;
    __syncthreads();

    int eg = blockIdx.x * 256 + t;           // < 524288
    int b = eg >> 14;
    int i = ei[eg], j = ej[eg];
    int ri = b * N_ + i, rj = b * N_ + j;

    float4 xi = *(const float4*)(x + ri * 4);
    float4 xj = *(const float4*)(x + rj * 4);
    float xdx = xi.x - xj.x, xdy = xi.y - xj.y, xdz = xi.z - xj.z, xdw = xi.w - xj.w;
    float nsq = xdx * xdx - xdy * xdy - xdz * xdz - xdw * xdw;
    float dsq = xi.x * xj.x - xi.y * xj.y - xi.z * xj.z - xi.w * xj.w;
    float norms = copysignf(log1pf(fabsf(nsq)), nsq);
    float dots  = copysignf(log1pf(fabsf(dsq)), dsq);

    const float4* pt4 = (const float4*)(Ptop + (size_t)ri * 72);
    const float4* pm4 = (const float4*)(Pmid + (size_t)rj * 72);
    const float* w144 = We1 + 144 * 72;
    const float* w145 = We1 + 145 * 72;
    float4* zr = (float4*)(z1 + (size_t)eg * 72);

    int slot = t & 31;
#pragma unroll
    for (int kc = 0; kc < 18; ++kc) {
        float4 a = pt4[kc];
        float4 bq = pm4[kc];
        float4 wa = *(const float4*)(w144 + 4 * kc);
        float4 wb = *(const float4*)(w145 + 4 * kc);
        float4 r;
        r.x = fmaf(norms, wa.x, fmaf(dots, wb.x, a.x + bq.x));
        r.y = fmaf(norms, wa.y, fmaf(dots, wb.y, a.y + bq.y));
        r.z = fmaf(norms, wa.z, fmaf(dots, wb.z, a.z + bq.z));
        r.w = fmaf(norms, wa.w, fmaf(dots, wb.w, a.w + bq.w));
        zr[kc] = r;
        int c0 = 4 * kc;
        atomicAdd(&ls[(c0 + 0) * 33 + slot], r.x);
        atomicAdd(&ls[(c0 + 1) * 33 + slot], r.y);
        atomicAdd(&ls[(c0 + 2) * 33 + slot], r.z);
        atomicAdd(&ls[(c0 + 3) * 33 + slot], r.w);
        atomicAdd(&ls[(72 + c0 + 0) * 33 + slot], r.x * r.x);
        atomicAdd(&ls[(72 + c0 + 1) * 33 + slot], r.y * r.y);
        atomicAdd(&ls[(72 + c0 + 2) * 33 + slot], r.z * r.z);
        atomicAdd(&ls[(72 + c0 + 3) * 33 + slot], r.w * r.w);
    }
    __syncthreads();
    for (int c = t; c < 144; c += 256) {
        float s = 0.f;
        for (int q = 0; q < 32; ++q) s += ls[c * 33 + q];
        atomicAdd(&gstats[c * 16], s);
    }
}

// -------------------- BN finalize (round-0 verbatim, stride-16 stats) --------------------
__global__ void k_fin(const float* __restrict__ gstats, const float* __restrict__ g,
                      const float* __restrict__ be, float* __restrict__ A,
                      float* __restrict__ Bv, float Minv)
{
    int c = threadIdx.x;
    if (c < 72) {
        float s = gstats[c * 16], sq = gstats[(72 + c) * 16];
        float mu = s * Minv;
        float var = sq * Minv - mu * mu;
        float inv = rsqrtf(var + EPS_);
        float a = g[c] * inv;
        A[c] = a;
        Bv[c] = be[c] - mu * a;
    }
}

// -------------------- edge pass 2 (ET=2): plain launch bounds -> no VGPR cap spill ----
__global__ __launch_bounds__(256) void k_edge2v3(
    const float* __restrict__ x,
    const int* __restrict__ ei, const int* __restrict__ ej,
    const float* __restrict__ We2, const float* __restrict__ be2,
    const float* __restrict__ Wm, const float* __restrict__ bm,
    const float* __restrict__ bx1, const float* __restrict__ Wx1T,
    const float* __restrict__ Wx2,
    const float* __restrict__ Ae, const float* __restrict__ Be,
    float* m_out,                       // z1 in, m out (in place, same thread)
    float* __restrict__ magg, float* __restrict__ agg, float* __restrict__ cnt)
{
    __shared__ float WS[5184];          // one 72x72 weight matrix (We2, then Wx1T)
    __shared__ float lmagg[128 * 73];
    __shared__ float lagg[128 * 5];
    __shared__ float lcnt[128];
    int t = threadIdx.x;
    for (int idx = t; idx < 128 * 73; idx += 256) lmagg[idx] = 0.f;
    for (int idx = t; idx < 128 * 5; idx += 256) lagg[idx] = 0.f;
    if (t < 128) lcnt[t] = 0.f;
    for (int idx = t; idx < 1296; idx += 256)
        ((float4*)WS)[idx] = ((const float4*)We2)[idx];
    __syncthreads();

    int b = blockIdx.x >> 5;
    int chunk = blockIdx.x & 31;
    int eg0 = b * E_ + chunk * 512 + t;
    int eg1 = eg0 + 256;
    float bm0 = bm[0];

    // ---- phase A: m = sigmoid-gated relu(relu(BN(z1)) @ We2 + be2), both edges ----
    const float4* zr0 = (const float4*)(m_out + (size_t)eg0 * 72);
    const float4* zr1 = (const float4*)(m_out + (size_t)eg1 * 72);
    float4 acc0[18], acc1[18];
#pragma unroll
    for (int cc = 0; cc < 18; ++cc) {
        float4 bv = *(const float4*)(be2 + cc * 4);
        acc0[cc] = bv; acc1[cc] = bv;
    }
    for (int kc = 0; kc < 18; ++kc) {           // not unrolled: keep I$ small
        float4 v0 = zr0[kc];
        float4 v1 = zr1[kc];
        int k0 = kc * 4;
        float4 A4 = *(const float4*)(Ae + k0);
        float4 B4 = *(const float4*)(Be + k0);
        float za0 = fmaxf(fmaf(v0.x, A4.x, B4.x), 0.f);
        float za1 = fmaxf(fmaf(v0.y, A4.y, B4.y), 0.f);
        float za2 = fmaxf(fmaf(v0.z, A4.z, B4.z), 0.f);
        float za3 = fmaxf(fmaf(v0.w, A4.w, B4.w), 0.f);
        float zb0 = fmaxf(fmaf(v1.x, A4.x, B4.x), 0.f);
        float zb1 = fmaxf(fmaf(v1.y, A4.y, B4.y), 0.f);
        float zb2 = fmaxf(fmaf(v1.z, A4.z, B4.z), 0.f);
        float zb3 = fmaxf(fmaf(v1.w, A4.w, B4.w), 0.f);
        const float* w0 = &WS[(k0 + 0) * 72];
        const float* w1 = &WS[(k0 + 1) * 72];
        const float* w2 = &WS[(k0 + 2) * 72];
        const float* w3 = &WS[(k0 + 3) * 72];
#pragma unroll
        for (int cc = 0; cc < 18; ++cc) {
            float4 a0 = *(const float4*)(w0 + cc * 4);
            float4 a1 = *(const float4*)(w1 + cc * 4);
            float4 a2 = *(const float4*)(w2 + cc * 4);
            float4 a3 = *(const float4*)(w3 + cc * 4);
            acc0[cc].x = fmaf(za0, a0.x, fmaf(za1, a1.x, fmaf(za2, a2.x, fmaf(za3, a3.x, acc0[cc].x))));
            acc0[cc].y = fmaf(za0, a0.y, fmaf(za1, a1.y, fmaf(za2, a2.y, fmaf(za3, a3.y, acc0[cc].y))));
            acc0[cc].z = fmaf(za0, a0.z, fmaf(za1, a1.z, fmaf(za2, a2.z, fmaf(za3, a3.z, acc0[cc].z))));
            acc0[cc].w = fmaf(za0, a0.w, fmaf(za1, a1.w, fmaf(za2, a2.w, fmaf(za3, a3.w, acc0[cc].w))));
            acc1[cc].x = fmaf(zb0, a0.x, fmaf(zb1, a1.x, fmaf(zb2, a2.x, fmaf(zb3, a3.x, acc1[cc].x))));
            acc1[cc].y = fmaf(zb0, a0.y, fmaf(zb1, a1.y, fmaf(zb2, a2.y, fmaf(zb3, a3.y, acc1[cc].y))));
            acc1[cc].z = fmaf(zb0, a0.z, fmaf(zb1, a1.z, fmaf(zb2, a2.z, fmaf(zb3, a3.z, acc1[cc].z))));
            acc1[cc].w = fmaf(zb0, a0.w, fmaf(zb1, a1.w, fmaf(zb2, a2.w, fmaf(zb3, a3.w, acc1[cc].w))));
        }
    }
    float wdot0 = bm0, wdot1 = bm0;
#pragma unroll
    for (int cc = 0; cc < 18; ++cc) {
        acc0[cc].x = fmaxf(acc0[cc].x, 0.f); acc0[cc].y = fmaxf(acc0[cc].y, 0.f);
        acc0[cc].z = fmaxf(acc0[cc].z, 0.f); acc0[cc].w = fmaxf(acc0[cc].w, 0.f);
        acc1[cc].x = fmaxf(acc1[cc].x, 0.f); acc1[cc].y = fmaxf(acc1[cc].y, 0.f);
        acc1[cc].z = fmaxf(acc1[cc].z, 0.f); acc1[cc].w = fmaxf(acc1[cc].w, 0.f);
        float4 wm4 = *(const float4*)(Wm + cc * 4);
        wdot0 = fmaf(acc0[cc].x, wm4.x, fmaf(acc0[cc].y, wm4.y,
                fmaf(acc0[cc].z, wm4.z, fmaf(acc0[cc].w, wm4.w, wdot0))));
        wdot1 = fmaf(acc1[cc].x, wm4.x, fmaf(acc1[cc].y, wm4.y,
                fmaf(acc1[cc].z, wm4.z, fmaf(acc1[cc].w, wm4.w, wdot1))));
    }
    float sig0 = 1.f / (1.f + expf(-wdot0));
    float sig1 = 1.f / (1.f + expf(-wdot1));
    {
        float4* mw0 = (float4*)(m_out + (size_t)eg0 * 72);
        float4* mw1 = (float4*)(m_out + (size_t)eg1 * 72);
#pragma unroll
        for (int cc = 0; cc < 18; ++cc) {
            acc0[cc].x *= sig0; acc0[cc].y *= sig0; acc0[cc].z *= sig0; acc0[cc].w *= sig0;
            acc1[cc].x *= sig1; acc1[cc].y *= sig1; acc1[cc].z *= sig1; acc1[cc].w *= sig1;
            mw0[cc] = acc0[cc];
            mw1[cc] = acc1[cc];
        }
    }
    __syncthreads();
    for (int idx = t; idx < 1296; idx += 256)
        ((float4*)WS)[idx] = ((const float4*)Wx1T)[idx];
    __syncthreads();

    // ---- phase B: phi_x via Wx1T (m retained in acc0/acc1), trans, segment sums ----
    int i0 = ei[eg0], j0 = ej[eg0];
    int i1 = ei[eg1], j1 = ej[eg1];
    float4 xi0 = *(const float4*)(x + (b * N_ + i0) * 4);
    float4 xj0 = *(const float4*)(x + (b * N_ + j0) * 4);
    float4 xi1 = *(const float4*)(x + (b * N_ + i1) * 4);
    float4 xj1 = *(const float4*)(x + (b * N_ + j1) * 4);

    float phix0 = 0.f, phix1 = 0.f;
    for (int c2c = 0; c2c < 18; ++c2c) {        // not unrolled
        int c20 = c2c * 4;
        float4 t0 = *(const float4*)(bx1 + c20);
        float4 t1 = t0;
        const float* w0 = &WS[(c20 + 0) * 72];
        const float* w1 = &WS[(c20 + 1) * 72];
        const float* w2 = &WS[(c20 + 2) * 72];
        const float* w3 = &WS[(c20 + 3) * 72];
#pragma unroll
        for (int cc = 0; cc < 18; ++cc) {
            float4 a0 = *(const float4*)(w0 + cc * 4);
            float4 a1 = *(const float4*)(w1 + cc * 4);
            float4 a2 = *(const float4*)(w2 + cc * 4);
            float4 a3 = *(const float4*)(w3 + cc * 4);
            float4 m0 = acc0[cc];
            float4 m1 = acc1[cc];
            t0.x = fmaf(m0.x, a0.x, fmaf(m0.y, a0.y, fmaf(m0.z, a0.z, fmaf(m0.w, a0.w, t0.x))));
            t0.y = fmaf(m0.x, a1.x, fmaf(m0.y, a1.y, fmaf(m0.z, a1.z, fmaf(m0.w, a1.w, t0.y))));
            t0.z = fmaf(m0.x, a2.x, fmaf(m0.y, a2.y, fmaf(m0.z, a2.z, fmaf(m0.w, a2.w, t0.z))));
            t0.w = fmaf(m0.x, a3.x, fmaf(m0.y, a3.y, fmaf(m0.z, a3.z, fmaf(m0.w, a3.w, t0.w))));
            t1.x = fmaf(m1.x, a0.x, fmaf(m1.y, a0.y, fmaf(m1.z, a0.z, fmaf(m1.w, a0.w, t1.x))));
            t1.y = fmaf(m1.x, a1.x, fmaf(m1.y, a1.y, fmaf(m1.z, a1.z, fmaf(m1.w, a1.w, t1.y))));
            t1.z = fmaf(m1.x, a2.x, fmaf(m1.y, a2.y, fmaf(m1.z, a2.z, fmaf(m1.w, a2.w, t1.z))));
            t1.w = fmaf(m1.x, a3.x, fmaf(m1.y, a3.y, fmaf(m1.z, a3.z, fmaf(m1.w, a3.w, t1.w))));
        }
        float4 wx2v = *(const float4*)(Wx2 + c20);
        phix0 = fmaf(fmaxf(t0.x, 0.f), wx2v.x, phix0);
        phix0 = fmaf(fmaxf(t0.y, 0.f), wx2v.y, phix0);
        phix0 = fmaf(fmaxf(t0.z, 0.f), wx2v.z, phix0);
        phix0 = fmaf(fmaxf(t0.w, 0.f), wx2v.w, phix0);
        phix1 = fmaf(fmaxf(t1.x, 0.f), wx2v.x, phix1);
        phix1 = fmaf(fmaxf(t1.y, 0.f), wx2v.y, phix1);
        phix1 = fmaf(fmaxf(t1.z, 0.f), wx2v.z, phix1);
        phix1 = fmaf(fmaxf(t1.w, 0.f), wx2v.w, phix1);
    }
    {
        float trx = fminf(fmaxf((xi0.x - xj0.x) * phix0, -100.f), 100.f);
        float try_ = fminf(fmaxf((xi0.y - xj0.y) * phix0, -100.f), 100.f);
        float trz = fminf(fmaxf((xi0.z - xj0.z) * phix0, -100.f), 100.f);
        float trw = fminf(fmaxf((xi0.w - xj0.w) * phix0, -100.f), 100.f);
        atomicAdd(&lcnt[i0], 1.f);
        atomicAdd(&lagg[i0 * 5 + 0], trx);
        atomicAdd(&lagg[i0 * 5 + 1], try_);
        atomicAdd(&lagg[i0 * 5 + 2], trz);
        atomicAdd(&lagg[i0 * 5 + 3], trw);
        int base = i0 * 73;
#pragma unroll
        for (int cc = 0; cc < 18; ++cc) {
            atomicAdd(&lmagg[base + 4 * cc + 0], acc0[cc].x);
            atomicAdd(&lmagg[base + 4 * cc + 1], acc0[cc].y);
            atomicAdd(&lmagg[base + 4 * cc + 2], acc0[cc].z);
            atomicAdd(&lmagg[base + 4 * cc + 3], acc0[cc].w);
        }
    }
    {
        float trx = fminf(fmaxf((xi1.x - xj1.x) * phix1, -100.f), 100.f);
        float try_ = fminf(fmaxf((xi1.y - xj1.y) * phix1, -100.f), 100.f);
        float trz = fminf(fmaxf((xi1.z - xj1.z) * phix1, -100.f), 100.f);
        float trw = fminf(fmaxf((xi1.w - xj1.w) * phix1, -100.f), 100.f);
        atomicAdd(&lcnt[i1], 1.f);
        atomicAdd(&lagg[i1 * 5 + 0], trx);
        atomicAdd(&lagg[i1 * 5 + 1], try_);
        atomicAdd(&lagg[i1 * 5 + 2], trz);
        atomicAdd(&lagg[i1 * 5 + 3], trw);
        int base = i1 * 73;
#pragma unroll
        for (int cc = 0; cc < 18; ++cc) {
            atomicAdd(&lmagg[base + 4 * cc + 0], acc1[cc].x);
            atomicAdd(&lmagg[base + 4 * cc + 1], acc1[cc].y);
            atomicAdd(&lmagg[base + 4 * cc + 2], acc1[cc].z);
            atomicAdd(&lmagg[base + 4 * cc + 3], acc1[cc].w);
        }
    }
    __syncthreads();

    int nb = b * N_;
    for (int idx = t; idx < 128 * 72; idx += 256) {
        int n = idx / 72, c = idx - n * 72;
        float v = lmagg[n * 73 + c];
        if (v != 0.f) atomicAdd(&magg[(nb + n) * 72 + c], v);
    }
    for (int idx = t; idx < 128 * 4; idx += 256) {
        int n = idx >> 2, d = idx & 3;
        float v = lagg[n * 5 + d];
        if (v != 0.f) atomicAdd(&agg[(nb + n) * 4 + d], v);
    }
    if (t < 128) {
        float v = lcnt[t];
        if (v != 0.f) atomicAdd(&cnt[nb + t], v);
    }
}

// -------------------- round-0 k_node1 (verbatim, proven) --------------------
__global__ __launch_bounds__(256) void k_node1(
    const float* __restrict__ h, const float* __restrict__ magg,
    const float* __restrict__ attr, const float* __restrict__ Wh1,
    const float* __restrict__ bh1,
    float* __restrict__ zh1, float* __restrict__ gstats)
{
    __shared__ float ls[144 * 33];
    int t = threadIdx.x;
    for (int idx = t; idx < 144 * 33; idx += 256) ls[idx] = 0.f;
    __syncthreads();

    int row = blockIdx.x * 256 + t;   // < 4096
    float acc[72];
#pragma unroll
    for (int c = 0; c < 72; ++c) acc[c] = bh1[c];

    const float4* h4 = (const float4*)(h + row * 72);
    for (int kc = 0; kc < 18; ++kc) {
        float4 a = h4[kc];
        const float* wr = Wh1 + (kc * 4) * 72;
#pragma unroll
        for (int c = 0; c < 72; ++c)
            acc[c] = fmaf(a.x, wr[c], fmaf(a.y, wr[72 + c], fmaf(a.z, wr[144 + c], fmaf(a.w, wr[216 + c], acc[c]))));
    }
    const float4* mg4 = (const float4*)(magg + row * 72);
    for (int kc = 0; kc < 18; ++kc) {
        float4 a = mg4[kc];
        const float* wr = Wh1 + ((72 + kc * 4)) * 72;
#pragma unroll
        for (int c = 0; c < 72; ++c)
            acc[c] = fmaf(a.x, wr[c], fmaf(a.y, wr[72 + c], fmaf(a.z, wr[144 + c], fmaf(a.w, wr[216 + c], acc[c]))));
    }
    const float4* at4 = (const float4*)(attr + row * 8);
    for (int kc = 0; kc < 2; ++kc) {
        float4 a = at4[kc];
        const float* wr = Wh1 + ((144 + kc * 4)) * 72;
#pragma unroll
        for (int c = 0; c < 72; ++c)
            acc[c] = fmaf(a.x, wr[c], fmaf(a.y, wr[72 + c], fmaf(a.z, wr[144 + c], fmaf(a.w, wr[216 + c], acc[c]))));
    }

    float4* zr = (float4*)(zh1 + row * 72);
#pragma unroll
    for (int kc = 0; kc < 18; ++kc)
        zr[kc] = make_float4(acc[4 * kc], acc[4 * kc + 1], acc[4 * kc + 2], acc[4 * kc + 3]);

    int slot = t & 31;
#pragma unroll
    for (int c = 0; c < 72; ++c) {
        atomicAdd(&ls[c * 33 + slot], acc[c]);
        atomicAdd(&ls[(72 + c) * 33 + slot], acc[c] * acc[c]);
    }
    __syncthreads();
    for (int c = t; c < 144; c += 256) {
        float s = 0.f;
        for (int q = 0; q < 32; ++q) s += ls[c * 33 + q];
        atomicAdd(&gstats[c * 16], s);
    }
}

// -------------------- round-0 k_node2 (verbatim, proven) --------------------
__global__ __launch_bounds__(256) void k_node2(
    const float* __restrict__ h, const float* __restrict__ x,
    const float* __restrict__ zh1,
    const float* __restrict__ Ah, const float* __restrict__ Bh,
    const float* __restrict__ Wh2, const float* __restrict__ bh2,
    const float* __restrict__ agg, const float* __restrict__ cnt,
    float* __restrict__ hout, float* __restrict__ xout)
{
    int row = blockIdx.x * 256 + threadIdx.x;   // < 4096
    float acc[72];
#pragma unroll
    for (int c = 0; c < 72; ++c) acc[c] = bh2[c];

    const float4* z4 = (const float4*)(zh1 + row * 72);
    for (int kc = 0; kc < 18; ++kc) {
        float4 v = z4[kc];
        int k0 = kc * 4;
        float z0 = fmaxf(fmaf(v.x, Ah[k0],     Bh[k0]),     0.f);
        float z1v = fmaxf(fmaf(v.y, Ah[k0 + 1], Bh[k0 + 1]), 0.f);
        float z2v = fmaxf(fmaf(v.z, Ah[k0 + 2], Bh[k0 + 2]), 0.f);
        float z3v = fmaxf(fmaf(v.w, Ah[k0 + 3], Bh[k0 + 3]), 0.f);
        const float* w0 = Wh2 + k0 * 72;
#pragma unroll
        for (int c = 0; c < 72; ++c)
            acc[c] = fmaf(z0, w0[c], fmaf(z1v, w0[72 + c], fmaf(z2v, w0[144 + c], fmaf(z3v, w0[216 + c], acc[c]))));
    }
    const float4* hr = (const float4*)(h + row * 72);
    float4* ho = (float4*)(hout + row * 72);
#pragma unroll
    for (int kc = 0; kc < 18; ++kc) {
        float4 hv = hr[kc];
        ho[kc] = make_float4(hv.x + acc[4 * kc], hv.y + acc[4 * kc + 1],
                             hv.z + acc[4 * kc + 2], hv.w + acc[4 * kc + 3]);
    }
    float inv = 1.f / fmaxf(cnt[row], 1.f);
    float4 xv = *(const float4*)(x + row * 4);
    float4 av = *(const float4*)(agg + row * 4);
    *(float4*)(xout + row * 4) = make_float4(xv.x + av.x * inv, xv.y + av.y * inv,
                                             xv.z + av.z * inv, xv.w + av.w * inv);
}

extern "C" void kernel_launch(void* const* d_in, const int* in_sizes, int n_in,
                              void* d_out, int out_size, void* d_ws, size_t ws_size,
                              hipStream_t stream) {
    const float* h    = (const float*)d_in[0];
    const float* x    = (const float*)d_in[1];
    const int*   ei   = (const int*)d_in[2];
    const int*   ej   = (const int*)d_in[3];
    const float* attr = (const float*)d_in[4];
    const float* We1  = (const float*)d_in[5];
    const float* ge   = (const float*)d_in[6];
    const float* bee  = (const float*)d_in[7];
    const float* We2  = (const float*)d_in[8];
    const float* be2  = (const float*)d_in[9];
    const float* Wm   = (const float*)d_in[10];
    const float* bm   = (const float*)d_in[11];
    const float* Wx1  = (const float*)d_in[12];
    const float* bx1  = (const float*)d_in[13];
    const float* Wx2  = (const float*)d_in[14];
    const float* Wh1  = (const float*)d_in[15];
    const float* bh1  = (const float*)d_in[16];
    const float* gh   = (const float*)d_in[17];
    const float* beh  = (const float*)d_in[18];
    const float* Wh2  = (const float*)d_in[19];
    const float* bh2  = (const float*)d_in[20];

    float* out  = (float*)d_out;
    float* hout = out + HOUT_OFF;
    float* xout = out + XOUT_OFF;
    float* mz   = out + M_OFF;          // z1 (fp32), then m (fp32), in place
    float* ws   = (float*)d_ws;

    hipMemsetAsync(ws, 0, (size_t)WS_ZERO_END * 4, stream);
    // MFMA canary: writes 256 floats into ZH1 region (dead until k_node1 overwrites it)
    k_canary<<<1, 64, 0, stream>>>(We1, ws + WS_ZH1);
    k_transpose<<<21, 256, 0, stream>>>(Wx1, ws + WS_WX1T);
    // P_top lives in the (currently dead) ZH1 region; P_mid in the MAGG region
    k_nodeproj<<<128, 256, 0, stream>>>(h, We1, ws + WS_ZH1, ws + WS_MAGG);
    k_edge1v2<<<2048, 256, 0, stream>>>(x, ei, ej, ws + WS_ZH1, ws + WS_MAGG, We1,
                                        mz, ws + WS_STATS_E);
    k_fin<<<1, 128, 0, stream>>>(ws + WS_STATS_E, ge, bee, ws + WS_AE, ws + WS_BE,
                                 1.0f / (float)(B_ * E_));
    // re-zero magg (P_mid is dead now; k_edge2v3 atomically accumulates into it)
    hipMemsetAsync(ws + WS_MAGG, 0, (size_t)(B_ * N_ * 72) * 4, stream);
    k_edge2v3<<<1024, 256, 0, stream>>>(x, ei, ej, We2, be2, Wm, bm, bx1, ws + WS_WX1T,
                                        Wx2, ws + WS_AE, ws + WS_BE, mz,
                                        ws + WS_MAGG, ws + WS_AGG, ws + WS_CNT);
    k_node1<<<16, 256, 0, stream>>>(h, ws + WS_MAGG, attr, Wh1, bh1,
                                    ws + WS_ZH1, ws + WS_STATS_H);
    k_fin<<<1, 128, 0, stream>>>(ws + WS_STATS_H, gh, beh, ws + WS_AH, ws + WS_BH,
                                 1.0f / 4096.0f);
    k_node2<<<16, 256, 0, stream>>>(h, x, ws + WS_ZH1, ws + WS_AH, ws + WS_BH, Wh2, bh2,
                                    ws + WS_AGG, ws + WS_CNT, hout, xout);
}

// Round 9
// 926.321 us; speedup vs baseline: 1.1656x; 1.1656x over previous
//
#include <hip/hip_runtime.h>
#include <math.h>

#define B_ 32
#define N_ 128
#define E_ 16384
#define EPS_ 1e-5f

typedef short short8v __attribute__((ext_vector_type(8)));
typedef float f32x4v __attribute__((ext_vector_type(4)));

// ---- ws layout (float offsets): within round-0 proven footprint ----
#define WS_STATS_E 0        // (unused now, kept for layout stability)
#define WS_STATS_H 2304
#define WS_MAGG    4608     // B*N*72  (Pmid, then stats partials, then magg)
#define WS_AGG     299520   // B*N*4
#define WS_CNT     315904   // B*N
#define WS_ZERO_END 320000
#define WS_AE      320000
#define WS_BE      320072
#define WS_AH      320144
#define WS_BH      320216
#define WS_WX1T    320288   // 72*72 transposed
#define WS_ZH1     325472   // B*N*72  (canary scratch, then P_top, then zh1)
// total = 620384 floats == round-0 proven footprint

#define HOUT_OFF 0
#define XOUT_OFF 294912
#define M_OFF    311296

#define NSTAT_T 36864       // stats threads: 144 blocks x 256; 36864 % 72 == 0

static __device__ __forceinline__ short f2bf(float f) {
    unsigned int u = __builtin_bit_cast(unsigned int, f);
    u += 0x7FFFu + ((u >> 16) & 1u);
    return (short)(u >> 16);
}

// -------------------- MFMA canary (passed round 7; keep as guard) --------------------
__global__ void k_canary(const float* __restrict__ src, float* __restrict__ dst) {
    __shared__ short As[16 * 32];
    __shared__ short Bs[16 * 32];
    int l = threadIdx.x;
    for (int idx = l; idx < 512; idx += 64) {
        As[idx] = f2bf(src[idx]);
        Bs[idx] = f2bf(src[512 + idx]);
    }
    __syncthreads();
    int ln = l & 15, g4 = l >> 4;
    short8v a = *(const short8v*)&As[ln * 32 + g4 * 8];
    short8v b = *(const short8v*)&Bs[ln * 32 + g4 * 8];
    f32x4v acc = {0.f, 0.f, 0.f, 0.f};
    acc = __builtin_amdgcn_mfma_f32_16x16x32_bf16(a, b, acc, 0, 0, 0);
#pragma unroll
    for (int r = 0; r < 4; ++r) dst[(g4 * 4 + r) * 16 + ln] = acc[r];
}

// -------------------- prep: transpose W_x1 --------------------
__global__ void k_transpose(const float* __restrict__ Wx1, float* __restrict__ WT) {
    int idx = blockIdx.x * 256 + threadIdx.x;
    if (idx < 72 * 72) {
        int r = idx / 72, c = idx - r * 72;
        WT[c * 72 + r] = Wx1[idx];
    }
}

// ---- node projections: P_top = h@We1[0:72], P_mid = h@We1[72:144], c-quartered ----
__global__ __launch_bounds__(256) void k_nodeproj(
    const float* __restrict__ h, const float* __restrict__ We1,
    float* __restrict__ Ptop, float* __restrict__ Pmid)
{
    int gid = blockIdx.x * 256 + threadIdx.x;    // < 32768
    int which = gid >> 14;
    int rem = gid & 16383;
    int row = rem >> 2;
    int q = rem & 3;
    int c0 = q * 18;
    const float4* h4 = (const float4*)(h + (size_t)row * 72);
    const float* base = We1 + which * 5184 + c0;
    float acc[18];
#pragma unroll
    for (int c = 0; c < 18; ++c) acc[c] = 0.f;
    for (int kc = 0; kc < 18; ++kc) {
        float4 a = h4[kc];
        const float* wr = base + (kc * 4) * 72;
#pragma unroll
        for (int c = 0; c < 18; ++c)
            acc[c] = fmaf(a.x, wr[c], fmaf(a.y, wr[72 + c], fmaf(a.z, wr[144 + c], fmaf(a.w, wr[216 + c], acc[c]))));
    }
    float* P = (which ? Pmid : Ptop) + (size_t)row * 72 + c0;
#pragma unroll
    for (int c = 0; c < 18; ++c) P[c] = acc[c];
}

// -------------------- edge pass 1 (NO stats): z1 = Pt[i]+Pm[j]+norms*w+dots*w ----------
__global__ __launch_bounds__(256) void k_edge1v3(
    const float* __restrict__ x,
    const int* __restrict__ ei, const int* __restrict__ ej,
    const float* __restrict__ Ptop, const float* __restrict__ Pmid,
    const float* __restrict__ We1,
    float* __restrict__ z1)
{
    int eg = blockIdx.x * 256 + threadIdx.x;  // < 524288
    int b = eg >> 14;
    int i = ei[eg], j = ej[eg];
    int ri = b * N_ + i, rj = b * N_ + j;

    float4 xi = *(const float4*)(x + ri * 4);
    float4 xj = *(const float4*)(x + rj * 4);
    float xdx = xi.x - xj.x, xdy = xi.y - xj.y, xdz = xi.z - xj.z, xdw = xi.w - xj.w;
    float nsq = xdx * xdx - xdy * xdy - xdz * xdz - xdw * xdw;
    float dsq = xi.x * xj.x - xi.y * xj.y - xi.z * xj.z - xi.w * xj.w;
    float norms = copysignf(log1pf(fabsf(nsq)), nsq);
    float dots  = copysignf(log1pf(fabsf(dsq)), dsq);

    const float4* pt4 = (const float4*)(Ptop + (size_t)ri * 72);
    const float4* pm4 = (const float4*)(Pmid + (size_t)rj * 72);
    const float* w144 = We1 + 144 * 72;
    const float* w145 = We1 + 145 * 72;
    float4* zr = (float4*)(z1 + (size_t)eg * 72);

#pragma unroll
    for (int kc = 0; kc < 18; ++kc) {
        float4 a = pt4[kc];
        float4 bq = pm4[kc];
        float4 wa = *(const float4*)(w144 + 4 * kc);
        float4 wb = *(const float4*)(w145 + 4 * kc);
        float4 r;
        r.x = fmaf(norms, wa.x, fmaf(dots, wb.x, a.x + bq.x));
        r.y = fmaf(norms, wa.y, fmaf(dots, wb.y, a.y + bq.y));
        r.z = fmaf(norms, wa.z, fmaf(dots, wb.z, a.z + bq.z));
        r.w = fmaf(norms, wa.w, fmaf(dots, wb.w, a.w + bq.w));
        zr[kc] = r;
    }
}

// -------------------- channel-strided BN stats: thread == channel (mod 72) ------------
// src has rows of 72 channels; tid % 72 is constant across the stride (36864 % 72 == 0).
__global__ __launch_bounds__(256) void k_stats(
    const float* __restrict__ src, float* __restrict__ sPart,
    float* __restrict__ qPart, int iters)
{
    int tid = blockIdx.x * 256 + threadIdx.x;   // < 36864
    float s = 0.f, q = 0.f;
    size_t idx = tid;
    for (int it = 0; it < iters; ++it, idx += NSTAT_T) {
        float v = src[idx];
        s += v;
        q = fmaf(v, v, q);
    }
    sPart[tid] = s;
    qPart[tid] = q;
}

// -------------------- BN finalize from strided partials (512 per channel) -------------
__global__ void k_fin2(const float* __restrict__ sPart, const float* __restrict__ qPart,
                       const float* __restrict__ g, const float* __restrict__ be,
                       float* __restrict__ A, float* __restrict__ Bv, float Minv)
{
    int c = threadIdx.x;
    if (c < 72) {
        float s = 0.f, q = 0.f;
        for (int k = 0; k < 512; ++k) {
            s += sPart[c + 72 * k];
            q += qPart[c + 72 * k];
        }
        float mu = s * Minv;
        float var = q * Minv - mu * mu;
        float inv = rsqrtf(var + EPS_);
        float a = g[c] * inv;
        A[c] = a;
        Bv[c] = be[c] - mu * a;
    }
}

// -------------------- edge pass 2 (hybrid LDS + scalar/VMEM weight split) -------------
// Per kc, columns 0..35 come from LDS (WS2), columns 36..71 from global (uniform address
// -> scalar/VMEM pipe). Halves LDS-pipe instruction count vs round-5's 465us kernel.
__global__ __launch_bounds__(256) void k_edge2v4(
    const float* __restrict__ x,
    const int* __restrict__ ei, const int* __restrict__ ej,
    const float* __restrict__ We2, const float* __restrict__ be2,
    const float* __restrict__ Wm, const float* __restrict__ bm,
    const float* __restrict__ bx1, const float* __restrict__ Wx1T,
    const float* __restrict__ Wx2,
    const float* __restrict__ Ae, const float* __restrict__ Be,
    float* m_out,                       // z1 in, m out (in place, same thread)
    float* __restrict__ magg, float* __restrict__ agg, float* __restrict__ cnt)
{
    __shared__ float WS2[72 * 36];      // columns 0..35 of the active weight matrix
    __shared__ float lmagg[128 * 73];
    __shared__ float lagg[128 * 5];
    __shared__ float lcnt[128];
    int t = threadIdx.x;
    for (int idx = t; idx < 128 * 73; idx += 256) lmagg[idx] = 0.f;
    for (int idx = t; idx < 128 * 5; idx += 256) lagg[idx] = 0.f;
    if (t < 128) lcnt[t] = 0.f;
    for (int idx = t; idx < 648; idx += 256) {
        int row = idx / 9, gq = idx - row * 9;
        ((float4*)(WS2 + row * 36))[gq] = ((const float4*)(We2 + row * 72))[gq];
    }
    __syncthreads();

    int b = blockIdx.x >> 4;
    int chunk = blockIdx.x & 15;
    float bm0 = bm[0];

    // ---- phase A: m = sigmoid-gated relu(relu(BN(z1)) @ We2 + be2) ----
    for (int it = 0; it < 4; ++it) {
        int eg = b * E_ + chunk * 1024 + it * 256 + t;
        const float4* zrow = (const float4*)(m_out + (size_t)eg * 72);
        float4 acc4[18];
#pragma unroll
        for (int cc = 0; cc < 18; ++cc) acc4[cc] = *(const float4*)(be2 + cc * 4);

        for (int kc = 0; kc < 18; ++kc) {
            float4 v = zrow[kc];
            int k0 = kc * 4;
            float4 A4 = *(const float4*)(Ae + k0);
            float4 B4 = *(const float4*)(Be + k0);
            float z0 = fmaxf(fmaf(v.x, A4.x, B4.x), 0.f);
            float z1v = fmaxf(fmaf(v.y, A4.y, B4.y), 0.f);
            float z2v = fmaxf(fmaf(v.z, A4.z, B4.z), 0.f);
            float z3v = fmaxf(fmaf(v.w, A4.w, B4.w), 0.f);
            const float* l0 = &WS2[(k0 + 0) * 36];
            const float* l1 = &WS2[(k0 + 1) * 36];
            const float* l2 = &WS2[(k0 + 2) * 36];
            const float* l3 = &WS2[(k0 + 3) * 36];
#pragma unroll
            for (int cc = 0; cc < 9; ++cc) {
                float4 a0 = *(const float4*)(l0 + cc * 4);
                float4 a1 = *(const float4*)(l1 + cc * 4);
                float4 a2 = *(const float4*)(l2 + cc * 4);
                float4 a3 = *(const float4*)(l3 + cc * 4);
                acc4[cc].x = fmaf(z0, a0.x, fmaf(z1v, a1.x, fmaf(z2v, a2.x, fmaf(z3v, a3.x, acc4[cc].x))));
                acc4[cc].y = fmaf(z0, a0.y, fmaf(z1v, a1.y, fmaf(z2v, a2.y, fmaf(z3v, a3.y, acc4[cc].y))));
                acc4[cc].z = fmaf(z0, a0.z, fmaf(z1v, a1.z, fmaf(z2v, a2.z, fmaf(z3v, a3.z, acc4[cc].z))));
                acc4[cc].w = fmaf(z0, a0.w, fmaf(z1v, a1.w, fmaf(z2v, a2.w, fmaf(z3v, a3.w, acc4[cc].w))));
            }
            const float* g0 = We2 + (k0 + 0) * 72;
            const float* g1 = We2 + (k0 + 1) * 72;
            const float* g2 = We2 + (k0 + 2) * 72;
            const float* g3 = We2 + (k0 + 3) * 72;
#pragma unroll
            for (int cc = 9; cc < 18; ++cc) {
                float4 a0 = *(const float4*)(g0 + cc * 4);
                float4 a1 = *(const float4*)(g1 + cc * 4);
                float4 a2 = *(const float4*)(g2 + cc * 4);
                float4 a3 = *(const float4*)(g3 + cc * 4);
                acc4[cc].x = fmaf(z0, a0.x, fmaf(z1v, a1.x, fmaf(z2v, a2.x, fmaf(z3v, a3.x, acc4[cc].x))));
                acc4[cc].y = fmaf(z0, a0.y, fmaf(z1v, a1.y, fmaf(z2v, a2.y, fmaf(z3v, a3.y, acc4[cc].y))));
                acc4[cc].z = fmaf(z0, a0.z, fmaf(z1v, a1.z, fmaf(z2v, a2.z, fmaf(z3v, a3.z, acc4[cc].z))));
                acc4[cc].w = fmaf(z0, a0.w, fmaf(z1v, a1.w, fmaf(z2v, a2.w, fmaf(z3v, a3.w, acc4[cc].w))));
            }
        }
        float wdot = bm0;
#pragma unroll
        for (int cc = 0; cc < 18; ++cc) {
            acc4[cc].x = fmaxf(acc4[cc].x, 0.f);
            acc4[cc].y = fmaxf(acc4[cc].y, 0.f);
            acc4[cc].z = fmaxf(acc4[cc].z, 0.f);
            acc4[cc].w = fmaxf(acc4[cc].w, 0.f);
            float4 wm4 = *(const float4*)(Wm + cc * 4);
            wdot = fmaf(acc4[cc].x, wm4.x, fmaf(acc4[cc].y, wm4.y,
                   fmaf(acc4[cc].z, wm4.z, fmaf(acc4[cc].w, wm4.w, wdot))));
        }
        float wsig = 1.f / (1.f + expf(-wdot));
        float4* mw = (float4*)(m_out + (size_t)eg * 72);
#pragma unroll
        for (int cc = 0; cc < 18; ++cc) {
            float4 r = acc4[cc];
            mw[cc] = make_float4(r.x * wsig, r.y * wsig, r.z * wsig, r.w * wsig);
        }
    }
    __syncthreads();
    for (int idx = t; idx < 648; idx += 256) {
        int row = idx / 9, gq = idx - row * 9;
        ((float4*)(WS2 + row * 36))[gq] = ((const float4*)(Wx1T + row * 72))[gq];
    }
    __syncthreads();

    // ---- phase B: phi_x via Wx1T (hybrid), trans clamp, segment sums ----
    for (int it = 0; it < 4; ++it) {
        int el = chunk * 1024 + it * 256 + t;
        int eg = b * E_ + el;
        int i = ei[eg], j = ej[eg];
        float4 xi = *(const float4*)(x + (b * N_ + i) * 4);
        float4 xj = *(const float4*)(x + (b * N_ + j) * 4);
        float xdx = xi.x - xj.x, xdy = xi.y - xj.y, xdz = xi.z - xj.z, xdw = xi.w - xj.w;

        float4 mv[18];
        const float4* mr = (const float4*)(m_out + (size_t)eg * 72);
#pragma unroll
        for (int cc = 0; cc < 18; ++cc) mv[cc] = mr[cc];

        float phix = 0.f;
        for (int c2c = 0; c2c < 18; ++c2c) {
            int c20 = c2c * 4;
            float4 t4 = *(const float4*)(bx1 + c20);
            const float* l0 = &WS2[(c20 + 0) * 36];
            const float* l1 = &WS2[(c20 + 1) * 36];
            const float* l2 = &WS2[(c20 + 2) * 36];
            const float* l3 = &WS2[(c20 + 3) * 36];
#pragma unroll
            for (int cc = 0; cc < 9; ++cc) {
                float4 mvv = mv[cc];
                float4 a0 = *(const float4*)(l0 + cc * 4);
                float4 a1 = *(const float4*)(l1 + cc * 4);
                float4 a2 = *(const float4*)(l2 + cc * 4);
                float4 a3 = *(const float4*)(l3 + cc * 4);
                t4.x = fmaf(mvv.x, a0.x, fmaf(mvv.y, a0.y, fmaf(mvv.z, a0.z, fmaf(mvv.w, a0.w, t4.x))));
                t4.y = fmaf(mvv.x, a1.x, fmaf(mvv.y, a1.y, fmaf(mvv.z, a1.z, fmaf(mvv.w, a1.w, t4.y))));
                t4.z = fmaf(mvv.x, a2.x, fmaf(mvv.y, a2.y, fmaf(mvv.z, a2.z, fmaf(mvv.w, a2.w, t4.z))));
                t4.w = fmaf(mvv.x, a3.x, fmaf(mvv.y, a3.y, fmaf(mvv.z, a3.z, fmaf(mvv.w, a3.w, t4.w))));
            }
            const float* g0 = Wx1T + (c20 + 0) * 72;
            const float* g1 = Wx1T + (c20 + 1) * 72;
            const float* g2 = Wx1T + (c20 + 2) * 72;
            const float* g3 = Wx1T + (c20 + 3) * 72;
#pragma unroll
            for (int cc = 9; cc < 18; ++cc) {
                float4 mvv = mv[cc];
                float4 a0 = *(const float4*)(g0 + cc * 4);
                float4 a1 = *(const float4*)(g1 + cc * 4);
                float4 a2 = *(const float4*)(g2 + cc * 4);
                float4 a3 = *(const float4*)(g3 + cc * 4);
                t4.x = fmaf(mvv.x, a0.x, fmaf(mvv.y, a0.y, fmaf(mvv.z, a0.z, fmaf(mvv.w, a0.w, t4.x))));
                t4.y = fmaf(mvv.x, a1.x, fmaf(mvv.y, a1.y, fmaf(mvv.z, a1.z, fmaf(mvv.w, a1.w, t4.y))));
                t4.z = fmaf(mvv.x, a2.x, fmaf(mvv.y, a2.y, fmaf(mvv.z, a2.z, fmaf(mvv.w, a2.w, t4.z))));
                t4.w = fmaf(mvv.x, a3.x, fmaf(mvv.y, a3.y, fmaf(mvv.z, a3.z, fmaf(mvv.w, a3.w, t4.w))));
            }
            float4 wx2v = *(const float4*)(Wx2 + c20);
            phix = fmaf(fmaxf(t4.x, 0.f), wx2v.x, phix);
            phix = fmaf(fmaxf(t4.y, 0.f), wx2v.y, phix);
            phix = fmaf(fmaxf(t4.z, 0.f), wx2v.z, phix);
            phix = fmaf(fmaxf(t4.w, 0.f), wx2v.w, phix);
        }
        float trx = fminf(fmaxf(xdx * phix, -100.f), 100.f);
        float try_ = fminf(fmaxf(xdy * phix, -100.f), 100.f);
        float trz = fminf(fmaxf(xdz * phix, -100.f), 100.f);
        float trw = fminf(fmaxf(xdw * phix, -100.f), 100.f);

        atomicAdd(&lcnt[i], 1.f);
        atomicAdd(&lagg[i * 5 + 0], trx);
        atomicAdd(&lagg[i * 5 + 1], try_);
        atomicAdd(&lagg[i * 5 + 2], trz);
        atomicAdd(&lagg[i * 5 + 3], trw);
        int base = i * 73;
#pragma unroll
        for (int cc = 0; cc < 18; ++cc) {
            atomicAdd(&lmagg[base + 4 * cc + 0], mv[cc].x);
            atomicAdd(&lmagg[base + 4 * cc + 1], mv[cc].y);
            atomicAdd(&lmagg[base + 4 * cc + 2], mv[cc].z);
            atomicAdd(&lmagg[base + 4 * cc + 3], mv[cc].w);
        }
    }
    __syncthreads();

    int nb = b * N_;
    for (int idx = t; idx < 128 * 72; idx += 256) {
        int n = idx / 72, c = idx - n * 72;
        float v = lmagg[n * 73 + c];
        if (v != 0.f) atomicAdd(&magg[(nb + n) * 72 + c], v);
    }
    for (int idx = t; idx < 128 * 4; idx += 256) {
        int n = idx >> 2, d = idx & 3;
        float v = lagg[n * 5 + d];
        if (v != 0.f) atomicAdd(&agg[(nb + n) * 4 + d], v);
    }
    if (t < 128) {
        float v = lcnt[t];
        if (v != 0.f) atomicAdd(&cnt[nb + t], v);
    }
}

// -------------------- node1 (NO stats): cat @ Wh1 + bh1 -> zh1 --------------------
__global__ __launch_bounds__(256) void k_node1v2(
    const float* __restrict__ h, const float* __restrict__ magg,
    const float* __restrict__ attr, const float* __restrict__ Wh1,
    const float* __restrict__ bh1, float* __restrict__ zh1)
{
    int row = blockIdx.x * 256 + threadIdx.x;   // < 4096
    float acc[72];
#pragma unroll
    for (int c = 0; c < 72; ++c) acc[c] = bh1[c];

    const float4* h4 = (const float4*)(h + row * 72);
    for (int kc = 0; kc < 18; ++kc) {
        float4 a = h4[kc];
        const float* wr = Wh1 + (kc * 4) * 72;
#pragma unroll
        for (int c = 0; c < 72; ++c)
            acc[c] = fmaf(a.x, wr[c], fmaf(a.y, wr[72 + c], fmaf(a.z, wr[144 + c], fmaf(a.w, wr[216 + c], acc[c]))));
    }
    const float4* mg4 = (const float4*)(magg + row * 72);
    for (int kc = 0; kc < 18; ++kc) {
        float4 a = mg4[kc];
        const float* wr = Wh1 + ((72 + kc * 4)) * 72;
#pragma unroll
        for (int c = 0; c < 72; ++c)
            acc[c] = fmaf(a.x, wr[c], fmaf(a.y, wr[72 + c], fmaf(a.z, wr[144 + c], fmaf(a.w, wr[216 + c], acc[c]))));
    }
    const float4* at4 = (const float4*)(attr + row * 8);
    for (int kc = 0; kc < 2; ++kc) {
        float4 a = at4[kc];
        const float* wr = Wh1 + ((144 + kc * 4)) * 72;
#pragma unroll
        for (int c = 0; c < 72; ++c)
            acc[c] = fmaf(a.x, wr[c], fmaf(a.y, wr[72 + c], fmaf(a.z, wr[144 + c], fmaf(a.w, wr[216 + c], acc[c]))));
    }

    float4* zr = (float4*)(zh1 + row * 72);
#pragma unroll
    for (int kc = 0; kc < 18; ++kc)
        zr[kc] = make_float4(acc[4 * kc], acc[4 * kc + 1], acc[4 * kc + 2], acc[4 * kc + 3]);
}

// -------------------- node2: h_out, x_out (round-0 verbatim) --------------------
__global__ __launch_bounds__(256) void k_node2(
    const float* __restrict__ h, const float* __restrict__ x,
    const float* __restrict__ zh1,
    const float* __restrict__ Ah, const float* __restrict__ Bh,
    const float* __restrict__ Wh2, const float* __restrict__ bh2,
    const float* __restrict__ agg, const float* __restrict__ cnt,
    float* __restrict__ hout, float* __restrict__ xout)
{
    int row = blockIdx.x * 256 + threadIdx.x;   // < 4096
    float acc[72];
#pragma unroll
    for (int c = 0; c < 72; ++c) acc[c] = bh2[c];

    const float4* z4 = (const float4*)(zh1 + row * 72);
    for (int kc = 0; kc < 18; ++kc) {
        float4 v = z4[kc];
        int k0 = kc * 4;
        float z0 = fmaxf(fmaf(v.x, Ah[k0],     Bh[k0]),     0.f);
        float z1v = fmaxf(fmaf(v.y, Ah[k0 + 1], Bh[k0 + 1]), 0.f);
        float z2v = fmaxf(fmaf(v.z, Ah[k0 + 2], Bh[k0 + 2]), 0.f);
        float z3v = fmaxf(fmaf(v.w, Ah[k0 + 3], Bh[k0 + 3]), 0.f);
        const float* w0 = Wh2 + k0 * 72;
#pragma unroll
        for (int c = 0; c < 72; ++c)
            acc[c] = fmaf(z0, w0[c], fmaf(z1v, w0[72 + c], fmaf(z2v, w0[144 + c], fmaf(z3v, w0[216 + c], acc[c]))));
    }
    const float4* hr = (const float4*)(h + row * 72);
    float4* ho = (float4*)(hout + row * 72);
#pragma unroll
    for (int kc = 0; kc < 18; ++kc) {
        float4 hv = hr[kc];
        ho[kc] = make_float4(hv.x + acc[4 * kc], hv.y + acc[4 * kc + 1],
                             hv.z + acc[4 * kc + 2], hv.w + acc[4 * kc + 3]);
    }
    float inv = 1.f / fmaxf(cnt[row], 1.f);
    float4 xv = *(const float4*)(x + row * 4);
    float4 av = *(const float4*)(agg + row * 4);
    *(float4*)(xout + row * 4) = make_float4(xv.x + av.x * inv, xv.y + av.y * inv,
                                             xv.z + av.z * inv, xv.w + av.w * inv);
}

extern "C" void kernel_launch(void* const* d_in, const int* in_sizes, int n_in,
                              void* d_out, int out_size, void* d_ws, size_t ws_size,
                              hipStream_t stream) {
    const float* h    = (const float*)d_in[0];
    const float* x    = (const float*)d_in[1];
    const int*   ei   = (const int*)d_in[2];
    const int*   ej   = (const int*)d_in[3];
    const float* attr = (const float*)d_in[4];
    const float* We1  = (const float*)d_in[5];
    const float* ge   = (const float*)d_in[6];
    const float* bee  = (const float*)d_in[7];
    const float* We2  = (const float*)d_in[8];
    const float* be2  = (const float*)d_in[9];
    const float* Wm   = (const float*)d_in[10];
    const float* bm   = (const float*)d_in[11];
    const float* Wx1  = (const float*)d_in[12];
    const float* bx1  = (const float*)d_in[13];
    const float* Wx2  = (const float*)d_in[14];
    const float* Wh1  = (const float*)d_in[15];
    const float* bh1  = (const float*)d_in[16];
    const float* gh   = (const float*)d_in[17];
    const float* beh  = (const float*)d_in[18];
    const float* Wh2  = (const float*)d_in[19];
    const float* bh2  = (const float*)d_in[20];

    float* out  = (float*)d_out;
    float* hout = out + HOUT_OFF;
    float* xout = out + XOUT_OFF;
    float* mz   = out + M_OFF;          // z1 (fp32), then m (fp32), in place
    float* ws   = (float*)d_ws;

    hipMemsetAsync(ws, 0, (size_t)WS_ZERO_END * 4, stream);
    k_canary<<<1, 64, 0, stream>>>(We1, ws + WS_ZH1);
    k_transpose<<<21, 256, 0, stream>>>(Wx1, ws + WS_WX1T);
    // P_top in ZH1 region; P_mid in MAGG region (both dead later)
    k_nodeproj<<<128, 256, 0, stream>>>(h, We1, ws + WS_ZH1, ws + WS_MAGG);
    k_edge1v3<<<2048, 256, 0, stream>>>(x, ei, ej, ws + WS_ZH1, ws + WS_MAGG, We1, mz);
    // E-side BN stats: strided partials into MAGG region (P_mid is dead now)
    k_stats<<<144, 256, 0, stream>>>(mz, ws + WS_MAGG, ws + WS_MAGG + NSTAT_T, 1024);
    k_fin2<<<1, 128, 0, stream>>>(ws + WS_MAGG, ws + WS_MAGG + NSTAT_T, ge, bee,
                                  ws + WS_AE, ws + WS_BE, 1.0f / (float)(B_ * E_));
    // re-zero magg (stats partials dead; k_edge2v4 accumulates into it)
    hipMemsetAsync(ws + WS_MAGG, 0, (size_t)(B_ * N_ * 72) * 4, stream);
    k_edge2v4<<<512, 256, 0, stream>>>(x, ei, ej, We2, be2, Wm, bm, bx1, ws + WS_WX1T,
                                       Wx2, ws + WS_AE, ws + WS_BE, mz,
                                       ws + WS_MAGG, ws + WS_AGG, ws + WS_CNT);
    k_node1v2<<<16, 256, 0, stream>>>(h, ws + WS_MAGG, attr, Wh1, bh1, ws + WS_ZH1);
    // H-side BN stats: partials into the hout region (fully overwritten by k_node2)
    k_stats<<<144, 256, 0, stream>>>(ws + WS_ZH1, hout, hout + NSTAT_T, 8);
    k_fin2<<<1, 128, 0, stream>>>(hout, hout + NSTAT_T, gh, beh,
                                  ws + WS_AH, ws + WS_BH, 1.0f / 4096.0f);
    k_node2<<<16, 256, 0, stream>>>(h, x, ws + WS_ZH1, ws + WS_AH, ws + WS_BH, Wh2, bh2,
                                    ws + WS_AGG, ws + WS_CNT, hout, xout);
}

// Round 10
// 781.381 us; speedup vs baseline: 1.3818x; 1.1855x over previous
//
#include <hip/hip_runtime.h>
#include <math.h>

#define B_ 32
#define N_ 128
#define E_ 16384
#define EPS_ 1e-5f

typedef short short8v __attribute__((ext_vector_type(8)));
typedef float f32x4v __attribute__((ext_vector_type(4)));

// ---- ws layout (float offsets): round-0 proven footprint ----
#define WS_STATS_E 0
#define WS_STATS_H 2304
#define WS_MAGG    4608     // B*N*72  (Pmid, then stats partials, then magg)
#define WS_AGG     299520   // B*N*4
#define WS_CNT     315904   // B*N
#define WS_ZERO_END 320000
#define WS_AE      320000
#define WS_BE      320072
#define WS_AH      320144
#define WS_BH      320216
#define WS_WX1T    320288   // (unused this round)
#define WS_ZH1     325472   // B*N*72  (P_top, then zh1)

#define HOUT_OFF 0
#define XOUT_OFF 294912
#define M_OFF    311296

#define NSTAT_T 36864

static __device__ __forceinline__ short f2bf(float f) {
    unsigned int u = __builtin_bit_cast(unsigned int, f);
    u += 0x7FFFu + ((u >> 16) & 1u);
    return (short)(u >> 16);
}

// ---- node projections: P_top = h@We1[0:72], P_mid = h@We1[72:144], c-quartered ----
__global__ __launch_bounds__(256) void k_nodeproj(
    const float* __restrict__ h, const float* __restrict__ We1,
    float* __restrict__ Ptop, float* __restrict__ Pmid)
{
    int gid = blockIdx.x * 256 + threadIdx.x;    // < 32768
    int which = gid >> 14;
    int rem = gid & 16383;
    int row = rem >> 2;
    int q = rem & 3;
    int c0 = q * 18;
    const float4* h4 = (const float4*)(h + (size_t)row * 72);
    const float* base = We1 + which * 5184 + c0;
    float acc[18];
#pragma unroll
    for (int c = 0; c < 18; ++c) acc[c] = 0.f;
    for (int kc = 0; kc < 18; ++kc) {
        float4 a = h4[kc];
        const float* wr = base + (kc * 4) * 72;
#pragma unroll
        for (int c = 0; c < 18; ++c)
            acc[c] = fmaf(a.x, wr[c], fmaf(a.y, wr[72 + c], fmaf(a.z, wr[144 + c], fmaf(a.w, wr[216 + c], acc[c]))));
    }
    float* P = (which ? Pmid : Ptop) + (size_t)row * 72 + c0;
#pragma unroll
    for (int c = 0; c < 18; ++c) P[c] = acc[c];
}

// -------------------- edge pass 1: z1 = Pt[i]+Pm[j]+norms*w+dots*w --------------------
__global__ __launch_bounds__(256) void k_edge1v3(
    const float* __restrict__ x,
    const int* __restrict__ ei, const int* __restrict__ ej,
    const float* __restrict__ Ptop, const float* __restrict__ Pmid,
    const float* __restrict__ We1,
    float* __restrict__ z1)
{
    int eg = blockIdx.x * 256 + threadIdx.x;  // < 524288
    int b = eg >> 14;
    int i = ei[eg], j = ej[eg];
    int ri = b * N_ + i, rj = b * N_ + j;

    float4 xi = *(const float4*)(x + ri * 4);
    float4 xj = *(const float4*)(x + rj * 4);
    float xdx = xi.x - xj.x, xdy = xi.y - xj.y, xdz = xi.z - xj.z, xdw = xi.w - xj.w;
    float nsq = xdx * xdx - xdy * xdy - xdz * xdz - xdw * xdw;
    float dsq = xi.x * xj.x - xi.y * xj.y - xi.z * xj.z - xi.w * xj.w;
    float norms = copysignf(log1pf(fabsf(nsq)), nsq);
    float dots  = copysignf(log1pf(fabsf(dsq)), dsq);

    const float4* pt4 = (const float4*)(Ptop + (size_t)ri * 72);
    const float4* pm4 = (const float4*)(Pmid + (size_t)rj * 72);
    const float* w144 = We1 + 144 * 72;
    const float* w145 = We1 + 145 * 72;
    float4* zr = (float4*)(z1 + (size_t)eg * 72);

#pragma unroll
    for (int kc = 0; kc < 18; ++kc) {
        float4 a = pt4[kc];
        float4 bq = pm4[kc];
        float4 wa = *(const float4*)(w144 + 4 * kc);
        float4 wb = *(const float4*)(w145 + 4 * kc);
        float4 r;
        r.x = fmaf(norms, wa.x, fmaf(dots, wb.x, a.x + bq.x));
        r.y = fmaf(norms, wa.y, fmaf(dots, wb.y, a.y + bq.y));
        r.z = fmaf(norms, wa.z, fmaf(dots, wb.z, a.z + bq.z));
        r.w = fmaf(norms, wa.w, fmaf(dots, wb.w, a.w + bq.w));
        zr[kc] = r;
    }
}

// -------------------- channel-strided BN stats --------------------
__global__ __launch_bounds__(256) void k_stats(
    const float* __restrict__ src, float* __restrict__ sPart,
    float* __restrict__ qPart, int iters)
{
    int tid = blockIdx.x * 256 + threadIdx.x;   // < 36864
    float s = 0.f, q = 0.f;
    size_t idx = tid;
    for (int it = 0; it < iters; ++it, idx += NSTAT_T) {
        float v = src[idx];
        s += v;
        q = fmaf(v, v, q);
    }
    sPart[tid] = s;
    qPart[tid] = q;
}

__global__ void k_fin2(const float* __restrict__ sPart, const float* __restrict__ qPart,
                       const float* __restrict__ g, const float* __restrict__ be,
                       float* __restrict__ A, float* __restrict__ Bv, float Minv)
{
    int c = threadIdx.x;
    if (c < 72) {
        float s = 0.f, q = 0.f;
        for (int k = 0; k < 512; ++k) {
            s += sPart[c + 72 * k];
            q += qPart[c + 72 * k];
        }
        float mu = s * Minv;
        float var = q * Minv - mu * mu;
        float inv = rsqrtf(var + EPS_);
        float a = g[c] * inv;
        A[c] = a;
        Bv[c] = be[c] - mu * a;
    }
}

// -------------------- edge pass 2 via MFMA --------------------
// Per wave: 16 subtiles of 16 edges. Phase A: z->BN->GEMM2(We2)->gate->m.
// Phase B: GEMM3(Wx1T)->phix->trans + lmagg. Weights staged bf16 in LDS (canary pattern).
__global__ __launch_bounds__(256) void k_e2m(
    const float* __restrict__ x,
    const int* __restrict__ ei, const int* __restrict__ ej,
    const float* __restrict__ We2, const float* __restrict__ be2,
    const float* __restrict__ Wm, const float* __restrict__ bm,
    const float* __restrict__ bx1, const float* __restrict__ Wx1,
    const float* __restrict__ Wx2,
    const float* __restrict__ Ae, const float* __restrict__ Be,
    float* mz,                           // z1 in, m out (same region)
    float* __restrict__ magg, float* __restrict__ agg, float* __restrict__ cnt)
{
    __shared__ short WtS[80 * 104];
    __shared__ float lmagg[128 * 73];
    __shared__ float lagg[128 * 5];
    __shared__ float lcnt[128];
    int t = threadIdx.x;
    for (int idx = t; idx < 128 * 73; idx += 256) lmagg[idx] = 0.f;
    for (int idx = t; idx < 128 * 5; idx += 256) lagg[idx] = 0.f;
    if (t < 128) lcnt[t] = 0.f;
    // stage We2^T bf16: WtS[n*104 + k] = We2[k*72+n]
    for (int idx = t; idx < 80 * 104; idx += 256) {
        int n = idx / 104, k = idx - n * 104;
        float v = (n < 72 && k < 72) ? We2[k * 72 + n] : 0.f;
        WtS[idx] = f2bf(v);
    }
    __syncthreads();

    int b = blockIdx.x >> 4, chunk = blockIdx.x & 15;
    int base = b * E_ + chunk * 1024;
    int w = t >> 6, l = t & 63, ln = l & 15, g4 = l >> 4;
    float bm0 = bm[0];

    // per-lane BN coefs for k-slices (k = ks*32 + g4*8 + e); ks=2 valid only for g4==0
    float4 a00 = *(const float4*)(Ae + g4 * 8),      a01 = *(const float4*)(Ae + g4 * 8 + 4);
    float4 b00 = *(const float4*)(Be + g4 * 8),      b01 = *(const float4*)(Be + g4 * 8 + 4);
    float4 a10 = *(const float4*)(Ae + 32 + g4 * 8), a11 = *(const float4*)(Ae + 32 + g4 * 8 + 4);
    float4 b10 = *(const float4*)(Be + 32 + g4 * 8), b11 = *(const float4*)(Be + 32 + g4 * 8 + 4);
    float4 a20, a21, b20, b21;
    if (g4 == 0) {
        a20 = *(const float4*)(Ae + 64); a21 = *(const float4*)(Ae + 68);
        b20 = *(const float4*)(Be + 64); b21 = *(const float4*)(Be + 68);
    } else {
        a20 = make_float4(0, 0, 0, 0); a21 = a20; b20 = a20; b21 = a20;
    }
    // per-lane channel coefs (chan = nt*16 + ln)
    float be2v[5], wmv[5], bxv[5], wxv[5];
#pragma unroll
    for (int nt = 0; nt < 5; ++nt) {
        int chan = nt * 16 + ln;
        bool cv = chan < 72;
        be2v[nt] = cv ? be2[chan] : 0.f;
        wmv[nt]  = cv ? Wm[chan]  : 0.f;
        bxv[nt]  = cv ? bx1[chan] : 0.f;
        wxv[nt]  = cv ? Wx2[chan] : 0.f;
    }
    const short8v zero8 = {0, 0, 0, 0, 0, 0, 0, 0};

    // =================== phase A ===================
    for (int ts = 0; ts < 16; ++ts) {
        int es = base + w * 64 + (ts >> 2) * 256 + (ts & 3) * 16;
        const float* zrow = mz + (size_t)(es + ln) * 72 + g4 * 8;
        float4 z0a = *(const float4*)(zrow);
        float4 z0b = *(const float4*)(zrow + 4);
        float4 z1a = *(const float4*)(zrow + 32);
        float4 z1b = *(const float4*)(zrow + 36);
        short8v az0, az1, az2 = zero8;
        az0[0] = f2bf(fmaxf(fmaf(z0a.x, a00.x, b00.x), 0.f));
        az0[1] = f2bf(fmaxf(fmaf(z0a.y, a00.y, b00.y), 0.f));
        az0[2] = f2bf(fmaxf(fmaf(z0a.z, a00.z, b00.z), 0.f));
        az0[3] = f2bf(fmaxf(fmaf(z0a.w, a00.w, b00.w), 0.f));
        az0[4] = f2bf(fmaxf(fmaf(z0b.x, a01.x, b01.x), 0.f));
        az0[5] = f2bf(fmaxf(fmaf(z0b.y, a01.y, b01.y), 0.f));
        az0[6] = f2bf(fmaxf(fmaf(z0b.z, a01.z, b01.z), 0.f));
        az0[7] = f2bf(fmaxf(fmaf(z0b.w, a01.w, b01.w), 0.f));
        az1[0] = f2bf(fmaxf(fmaf(z1a.x, a10.x, b10.x), 0.f));
        az1[1] = f2bf(fmaxf(fmaf(z1a.y, a10.y, b10.y), 0.f));
        az1[2] = f2bf(fmaxf(fmaf(z1a.z, a10.z, b10.z), 0.f));
        az1[3] = f2bf(fmaxf(fmaf(z1a.w, a10.w, b10.w), 0.f));
        az1[4] = f2bf(fmaxf(fmaf(z1b.x, a11.x, b11.x), 0.f));
        az1[5] = f2bf(fmaxf(fmaf(z1b.y, a11.y, b11.y), 0.f));
        az1[6] = f2bf(fmaxf(fmaf(z1b.z, a11.z, b11.z), 0.f));
        az1[7] = f2bf(fmaxf(fmaf(z1b.w, a11.w, b11.w), 0.f));
        if (g4 == 0) {
            float4 z2a = *(const float4*)(mz + (size_t)(es + ln) * 72 + 64);
            float4 z2b = *(const float4*)(mz + (size_t)(es + ln) * 72 + 68);
            az2[0] = f2bf(fmaxf(fmaf(z2a.x, a20.x, b20.x), 0.f));
            az2[1] = f2bf(fmaxf(fmaf(z2a.y, a20.y, b20.y), 0.f));
            az2[2] = f2bf(fmaxf(fmaf(z2a.z, a20.z, b20.z), 0.f));
            az2[3] = f2bf(fmaxf(fmaf(z2a.w, a20.w, b20.w), 0.f));
            az2[4] = f2bf(fmaxf(fmaf(z2b.x, a21.x, b21.x), 0.f));
            az2[5] = f2bf(fmaxf(fmaf(z2b.y, a21.y, b21.y), 0.f));
            az2[6] = f2bf(fmaxf(fmaf(z2b.z, a21.z, b21.z), 0.f));
            az2[7] = f2bf(fmaxf(fmaf(z2b.w, a21.w, b21.w), 0.f));
        }

        f32x4v acc[5];
#pragma unroll
        for (int nt = 0; nt < 5; ++nt) { f32x4v zz = {0.f, 0.f, 0.f, 0.f}; acc[nt] = zz; }
#pragma unroll
        for (int nt = 0; nt < 5; ++nt) {
            int rb = (nt * 16 + ln) * 104 + g4 * 8;
            short8v b0 = *(const short8v*)&WtS[rb];
            short8v b1 = *(const short8v*)&WtS[rb + 32];
            short8v b2 = *(const short8v*)&WtS[rb + 64];
            acc[nt] = __builtin_amdgcn_mfma_f32_16x16x32_bf16(az0, b0, acc[nt], 0, 0, 0);
            acc[nt] = __builtin_amdgcn_mfma_f32_16x16x32_bf16(az1, b1, acc[nt], 0, 0, 0);
            acc[nt] = __builtin_amdgcn_mfma_f32_16x16x32_bf16(az2, b2, acc[nt], 0, 0, 0);
        }

        float mt[5][4];
        float wdot[4] = {bm0, bm0, bm0, bm0};
#pragma unroll
        for (int nt = 0; nt < 5; ++nt) {
#pragma unroll
            for (int r = 0; r < 4; ++r) {
                mt[nt][r] = fmaxf(acc[nt][r] + be2v[nt], 0.f);
                wdot[r] = fmaf(mt[nt][r], wmv[nt], wdot[r]);
            }
        }
#pragma unroll
        for (int r = 0; r < 4; ++r) {
            wdot[r] += __shfl_xor(wdot[r], 1);
            wdot[r] += __shfl_xor(wdot[r], 2);
            wdot[r] += __shfl_xor(wdot[r], 4);
            wdot[r] += __shfl_xor(wdot[r], 8);
            wdot[r] = 1.f / (1.f + expf(-wdot[r]));
        }
#pragma unroll
        for (int nt = 0; nt < 5; ++nt) {
            int chan = nt * 16 + ln;
            if (chan < 72) {
#pragma unroll
                for (int r = 0; r < 4; ++r)
                    mz[(size_t)(es + g4 * 4 + r) * 72 + chan] = mt[nt][r] * wdot[r];
            }
        }
    }
    __syncthreads();
    // restage: Wx1^T bf16: WtS[c2*104 + c] = Wx1[c*72 + c2]
    for (int idx = t; idx < 80 * 104; idx += 256) {
        int n = idx / 104, k = idx - n * 104;
        float v = (n < 72 && k < 72) ? Wx1[k * 72 + n] : 0.f;
        WtS[idx] = f2bf(v);
    }
    __syncthreads();

    // =================== phase B ===================
    for (int ts = 0; ts < 16; ++ts) {
        int es = base + w * 64 + (ts >> 2) * 256 + (ts & 3) * 16;
        const float* mrow = mz + (size_t)(es + ln) * 72 + g4 * 8;
        float4 m0a = *(const float4*)(mrow);
        float4 m0b = *(const float4*)(mrow + 4);
        float4 m1a = *(const float4*)(mrow + 32);
        float4 m1b = *(const float4*)(mrow + 36);
        float4 m2a, m2b;
        short8v am0, am1, am2 = zero8;
        am0[0] = f2bf(m0a.x); am0[1] = f2bf(m0a.y); am0[2] = f2bf(m0a.z); am0[3] = f2bf(m0a.w);
        am0[4] = f2bf(m0b.x); am0[5] = f2bf(m0b.y); am0[6] = f2bf(m0b.z); am0[7] = f2bf(m0b.w);
        am1[0] = f2bf(m1a.x); am1[1] = f2bf(m1a.y); am1[2] = f2bf(m1a.z); am1[3] = f2bf(m1a.w);
        am1[4] = f2bf(m1b.x); am1[5] = f2bf(m1b.y); am1[6] = f2bf(m1b.z); am1[7] = f2bf(m1b.w);
        if (g4 == 0) {
            m2a = *(const float4*)(mz + (size_t)(es + ln) * 72 + 64);
            m2b = *(const float4*)(mz + (size_t)(es + ln) * 72 + 68);
            am2[0] = f2bf(m2a.x); am2[1] = f2bf(m2a.y); am2[2] = f2bf(m2a.z); am2[3] = f2bf(m2a.w);
            am2[4] = f2bf(m2b.x); am2[5] = f2bf(m2b.y); am2[6] = f2bf(m2b.z); am2[7] = f2bf(m2b.w);
        } else {
            m2a = make_float4(0, 0, 0, 0); m2b = m2a;
        }

        f32x4v acc[5];
#pragma unroll
        for (int nt = 0; nt < 5; ++nt) { f32x4v zz = {0.f, 0.f, 0.f, 0.f}; acc[nt] = zz; }
#pragma unroll
        for (int nt = 0; nt < 5; ++nt) {
            int rb = (nt * 16 + ln) * 104 + g4 * 8;
            short8v b0 = *(const short8v*)&WtS[rb];
            short8v b1 = *(const short8v*)&WtS[rb + 32];
            short8v b2 = *(const short8v*)&WtS[rb + 64];
            acc[nt] = __builtin_amdgcn_mfma_f32_16x16x32_bf16(am0, b0, acc[nt], 0, 0, 0);
            acc[nt] = __builtin_amdgcn_mfma_f32_16x16x32_bf16(am1, b1, acc[nt], 0, 0, 0);
            acc[nt] = __builtin_amdgcn_mfma_f32_16x16x32_bf16(am2, b2, acc[nt], 0, 0, 0);
        }

        float ph[4] = {0.f, 0.f, 0.f, 0.f};
#pragma unroll
        for (int nt = 0; nt < 5; ++nt) {
#pragma unroll
            for (int r = 0; r < 4; ++r)
                ph[r] = fmaf(fmaxf(acc[nt][r] + bxv[nt], 0.f), wxv[nt], ph[r]);
        }
#pragma unroll
        for (int r = 0; r < 4; ++r) {
            ph[r] += __shfl_xor(ph[r], 1);
            ph[r] += __shfl_xor(ph[r], 2);
            ph[r] += __shfl_xor(ph[r], 4);
            ph[r] += __shfl_xor(ph[r], 8);
        }
        if (ln == 0) {
#pragma unroll
            for (int r = 0; r < 4; ++r) {
                int eg = es + g4 * 4 + r;
                int ii = ei[eg], jj = ej[eg];
                float4 xi = *(const float4*)(x + (size_t)(b * N_ + ii) * 4);
                float4 xj = *(const float4*)(x + (size_t)(b * N_ + jj) * 4);
                float phx = ph[r];
                float trx = fminf(fmaxf((xi.x - xj.x) * phx, -100.f), 100.f);
                float try_ = fminf(fmaxf((xi.y - xj.y) * phx, -100.f), 100.f);
                float trz = fminf(fmaxf((xi.z - xj.z) * phx, -100.f), 100.f);
                float trw = fminf(fmaxf((xi.w - xj.w) * phx, -100.f), 100.f);
                atomicAdd(&lcnt[ii], 1.f);
                atomicAdd(&lagg[ii * 5 + 0], trx);
                atomicAdd(&lagg[ii * 5 + 1], try_);
                atomicAdd(&lagg[ii * 5 + 2], trz);
                atomicAdd(&lagg[ii * 5 + 3], trw);
            }
        }
        // lmagg: lane holds m[es+ln][k-slices]
        {
            int node = ei[es + ln];
            int kb0 = g4 * 8, kb1 = 32 + g4 * 8;
            int nb73 = node * 73;
            atomicAdd(&lmagg[nb73 + kb0 + 0], m0a.x);
            atomicAdd(&lmagg[nb73 + kb0 + 1], m0a.y);
            atomicAdd(&lmagg[nb73 + kb0 + 2], m0a.z);
            atomicAdd(&lmagg[nb73 + kb0 + 3], m0a.w);
            atomicAdd(&lmagg[nb73 + kb0 + 4], m0b.x);
            atomicAdd(&lmagg[nb73 + kb0 + 5], m0b.y);
            atomicAdd(&lmagg[nb73 + kb0 + 6], m0b.z);
            atomicAdd(&lmagg[nb73 + kb0 + 7], m0b.w);
            atomicAdd(&lmagg[nb73 + kb1 + 0], m1a.x);
            atomicAdd(&lmagg[nb73 + kb1 + 1], m1a.y);
            atomicAdd(&lmagg[nb73 + kb1 + 2], m1a.z);
            atomicAdd(&lmagg[nb73 + kb1 + 3], m1a.w);
            atomicAdd(&lmagg[nb73 + kb1 + 4], m1b.x);
            atomicAdd(&lmagg[nb73 + kb1 + 5], m1b.y);
            atomicAdd(&lmagg[nb73 + kb1 + 6], m1b.z);
            atomicAdd(&lmagg[nb73 + kb1 + 7], m1b.w);
            if (g4 == 0) {
                atomicAdd(&lmagg[nb73 + 64], m2a.x);
                atomicAdd(&lmagg[nb73 + 65], m2a.y);
                atomicAdd(&lmagg[nb73 + 66], m2a.z);
                atomicAdd(&lmagg[nb73 + 67], m2a.w);
                atomicAdd(&lmagg[nb73 + 68], m2b.x);
                atomicAdd(&lmagg[nb73 + 69], m2b.y);
                atomicAdd(&lmagg[nb73 + 70], m2b.z);
                atomicAdd(&lmagg[nb73 + 71], m2b.w);
            }
        }
    }
    __syncthreads();

    int nb = b * N_;
    for (int idx = t; idx < 128 * 72; idx += 256) {
        int n = idx / 72, c = idx - n * 72;
        float v = lmagg[n * 73 + c];
        if (v != 0.f) atomicAdd(&magg[(size_t)(nb + n) * 72 + c], v);
    }
    for (int idx = t; idx < 128 * 4; idx += 256) {
        int n = idx >> 2, d = idx & 3;
        float v = lagg[n * 5 + d];
        if (v != 0.f) atomicAdd(&agg[(nb + n) * 4 + d], v);
    }
    if (t < 128) {
        float v = lcnt[t];
        if (v != 0.f) atomicAdd(&cnt[nb + t], v);
    }
}

// -------------------- node1 (no stats) --------------------
__global__ __launch_bounds__(256) void k_node1v2(
    const float* __restrict__ h, const float* __restrict__ magg,
    const float* __restrict__ attr, const float* __restrict__ Wh1,
    const float* __restrict__ bh1, float* __restrict__ zh1)
{
    int row = blockIdx.x * 256 + threadIdx.x;   // < 4096
    float acc[72];
#pragma unroll
    for (int c = 0; c < 72; ++c) acc[c] = bh1[c];

    const float4* h4 = (const float4*)(h + row * 72);
    for (int kc = 0; kc < 18; ++kc) {
        float4 a = h4[kc];
        const float* wr = Wh1 + (kc * 4) * 72;
#pragma unroll
        for (int c = 0; c < 72; ++c)
            acc[c] = fmaf(a.x, wr[c], fmaf(a.y, wr[72 + c], fmaf(a.z, wr[144 + c], fmaf(a.w, wr[216 + c], acc[c]))));
    }
    const float4* mg4 = (const float4*)(magg + row * 72);
    for (int kc = 0; kc < 18; ++kc) {
        float4 a = mg4[kc];
        const float* wr = Wh1 + ((72 + kc * 4)) * 72;
#pragma unroll
        for (int c = 0; c < 72; ++c)
            acc[c] = fmaf(a.x, wr[c], fmaf(a.y, wr[72 + c], fmaf(a.z, wr[144 + c], fmaf(a.w, wr[216 + c], acc[c]))));
    }
    const float4* at4 = (const float4*)(attr + row * 8);
    for (int kc = 0; kc < 2; ++kc) {
        float4 a = at4[kc];
        const float* wr = Wh1 + ((144 + kc * 4)) * 72;
#pragma unroll
        for (int c = 0; c < 72; ++c)
            acc[c] = fmaf(a.x, wr[c], fmaf(a.y, wr[72 + c], fmaf(a.z, wr[144 + c], fmaf(a.w, wr[216 + c], acc[c]))));
    }

    float4* zr = (float4*)(zh1 + row * 72);
#pragma unroll
    for (int kc = 0; kc < 18; ++kc)
        zr[kc] = make_float4(acc[4 * kc], acc[4 * kc + 1], acc[4 * kc + 2], acc[4 * kc + 3]);
}

// -------------------- node2 --------------------
__global__ __launch_bounds__(256) void k_node2(
    const float* __restrict__ h, const float* __restrict__ x,
    const float* __restrict__ zh1,
    const float* __restrict__ Ah, const float* __restrict__ Bh,
    const float* __restrict__ Wh2, const float* __restrict__ bh2,
    const float* __restrict__ agg, const float* __restrict__ cnt,
    float* __restrict__ hout, float* __restrict__ xout)
{
    int row = blockIdx.x * 256 + threadIdx.x;   // < 4096
    float acc[72];
#pragma unroll
    for (int c = 0; c < 72; ++c) acc[c] = bh2[c];

    const float4* z4 = (const float4*)(zh1 + row * 72);
    for (int kc = 0; kc < 18; ++kc) {
        float4 v = z4[kc];
        int k0 = kc * 4;
        float z0 = fmaxf(fmaf(v.x, Ah[k0],     Bh[k0]),     0.f);
        float z1v = fmaxf(fmaf(v.y, Ah[k0 + 1], Bh[k0 + 1]), 0.f);
        float z2v = fmaxf(fmaf(v.z, Ah[k0 + 2], Bh[k0 + 2]), 0.f);
        float z3v = fmaxf(fmaf(v.w, Ah[k0 + 3], Bh[k0 + 3]), 0.f);
        const float* w0 = Wh2 + k0 * 72;
#pragma unroll
        for (int c = 0; c < 72; ++c)
            acc[c] = fmaf(z0, w0[c], fmaf(z1v, w0[72 + c], fmaf(z2v, w0[144 + c], fmaf(z3v, w0[216 + c], acc[c]))));
    }
    const float4* hr = (const float4*)(h + row * 72);
    float4* ho = (float4*)(hout + row * 72);
#pragma unroll
    for (int kc = 0; kc < 18; ++kc) {
        float4 hv = hr[kc];
        ho[kc] = make_float4(hv.x + acc[4 * kc], hv.y + acc[4 * kc + 1],
                             hv.z + acc[4 * kc + 2], hv.w + acc[4 * kc + 3]);
    }
    float inv = 1.f / fmaxf(cnt[row], 1.f);
    float4 xv = *(const float4*)(x + row * 4);
    float4 av = *(const float4*)(agg + row * 4);
    *(float4*)(xout + row * 4) = make_float4(xv.x + av.x * inv, xv.y + av.y * inv,
                                             xv.z + av.z * inv, xv.w + av.w * inv);
}

extern "C" void kernel_launch(void* const* d_in, const int* in_sizes, int n_in,
                              void* d_out, int out_size, void* d_ws, size_t ws_size,
                              hipStream_t stream) {
    const float* h    = (const float*)d_in[0];
    const float* x    = (const float*)d_in[1];
    const int*   ei   = (const int*)d_in[2];
    const int*   ej   = (const int*)d_in[3];
    const float* attr = (const float*)d_in[4];
    const float* We1  = (const float*)d_in[5];
    const float* ge   = (const float*)d_in[6];
    const float* bee  = (const float*)d_in[7];
    const float* We2  = (const float*)d_in[8];
    const float* be2  = (const float*)d_in[9];
    const float* Wm   = (const float*)d_in[10];
    const float* bm   = (const float*)d_in[11];
    const float* Wx1  = (const float*)d_in[12];
    const float* bx1  = (const float*)d_in[13];
    const float* Wx2  = (const float*)d_in[14];
    const float* Wh1  = (const float*)d_in[15];
    const float* bh1  = (const float*)d_in[16];
    const float* gh   = (const float*)d_in[17];
    const float* beh  = (const float*)d_in[18];
    const float* Wh2  = (const float*)d_in[19];
    const float* bh2  = (const float*)d_in[20];

    float* out  = (float*)d_out;
    float* hout = out + HOUT_OFF;
    float* xout = out + XOUT_OFF;
    float* mz   = out + M_OFF;          // z1 (fp32), then m (fp32), in place
    float* ws   = (float*)d_ws;

    hipMemsetAsync(ws, 0, (size_t)WS_ZERO_END * 4, stream);
    k_nodeproj<<<128, 256, 0, stream>>>(h, We1, ws + WS_ZH1, ws + WS_MAGG);
    k_edge1v3<<<2048, 256, 0, stream>>>(x, ei, ej, ws + WS_ZH1, ws + WS_MAGG, We1, mz);
    k_stats<<<144, 256, 0, stream>>>(mz, ws + WS_MAGG, ws + WS_MAGG + NSTAT_T, 1024);
    k_fin2<<<1, 128, 0, stream>>>(ws + WS_MAGG, ws + WS_MAGG + NSTAT_T, ge, bee,
                                  ws + WS_AE, ws + WS_BE, 1.0f / (float)(B_ * E_));
    hipMemsetAsync(ws + WS_MAGG, 0, (size_t)(B_ * N_ * 72) * 4, stream);
    k_e2m<<<512, 256, 0, stream>>>(x, ei, ej, We2, be2, Wm, bm, bx1, Wx1, Wx2,
                                   ws + WS_AE, ws + WS_BE, mz,
                                   ws + WS_MAGG, ws + WS_AGG, ws + WS_CNT);
    k_node1v2<<<16, 256, 0, stream>>>(h, ws + WS_MAGG, attr, Wh1, bh1, ws + WS_ZH1);
    k_stats<<<144, 256, 0, stream>>>(ws + WS_ZH1, hout, hout + NSTAT_T, 8);
    k_fin2<<<1, 128, 0, stream>>>(hout, hout + NSTAT_T, gh, beh,
                                  ws + WS_AH, ws + WS_BH, 1.0f / 4096.0f);
    k_node2<<<16, 256, 0, stream>>>(h, x, ws + WS_ZH1, ws + WS_AH, ws + WS_BH, Wh2, bh2,
                                    ws + WS_AGG, ws + WS_CNT, hout, xout);
}

// Round 11
// 685.414 us; speedup vs baseline: 1.5753x; 1.1400x over previous
//
#include <hip/hip_runtime.h>
#include <math.h>

#define B_ 32
#define N_ 128
#define E_ 16384
#define EPS_ 1e-5f

typedef short short8v __attribute__((ext_vector_type(8)));
typedef float f32x4v __attribute__((ext_vector_type(4)));

// ---- ws layout (float offsets): round-0 proven footprint ----
#define WS_MAGG    4608     // B*N*72  (Pmid, then stats partials, then magg)
#define WS_AGG     299520   // B*N*4
#define WS_CNT     315904   // B*N
#define WS_ZERO_END 320000
#define WS_AE      320000
#define WS_BE      320072
#define WS_AH      320144
#define WS_BH      320216
#define WS_ZH1     325472   // B*N*72  (P_top, then zh1)

#define HOUT_OFF 0
#define XOUT_OFF 294912
#define M_OFF    311296

#define NSTAT_T 36864

static __device__ __forceinline__ short f2bf(float f) {
    unsigned int u = __builtin_bit_cast(unsigned int, f);
    u += 0x7FFFu + ((u >> 16) & 1u);
    return (short)(u >> 16);
}

// ---- node projections (q/which block-uniform): P_top=h@We1[0:72], P_mid=h@We1[72:144] ----
__global__ __launch_bounds__(256) void k_nodeproj(
    const float* __restrict__ h, const float* __restrict__ We1,
    float* __restrict__ Ptop, float* __restrict__ Pmid)
{
    int blk = blockIdx.x;                 // 128
    int rowBlk = blk >> 3, sub = blk & 7;
    int which = sub >> 2, q = sub & 3;
    int row = rowBlk * 256 + threadIdx.x; // < 4096
    int c0 = q * 18;
    const float4* h4 = (const float4*)(h + (size_t)row * 72);
    const float* base = We1 + which * 5184 + c0;
    float acc[18];
#pragma unroll
    for (int c = 0; c < 18; ++c) acc[c] = 0.f;
    for (int kc = 0; kc < 18; ++kc) {
        float4 a = h4[kc];
        const float* wr = base + (kc * 4) * 72;
#pragma unroll
        for (int c = 0; c < 18; ++c)
            acc[c] = fmaf(a.x, wr[c], fmaf(a.y, wr[72 + c], fmaf(a.z, wr[144 + c], fmaf(a.w, wr[216 + c], acc[c]))));
    }
    float* P = (which ? Pmid : Ptop) + (size_t)row * 72 + c0;
#pragma unroll
    for (int c = 0; c < 18; ++c) P[c] = acc[c];
}

// -------------------- edge pass 1: z1 = Pt[i]+Pm[j]+norms*w+dots*w --------------------
__global__ __launch_bounds__(256) void k_edge1v3(
    const float* __restrict__ x,
    const int* __restrict__ ei, const int* __restrict__ ej,
    const float* __restrict__ Ptop, const float* __restrict__ Pmid,
    const float* __restrict__ We1,
    float* __restrict__ z1)
{
    int eg = blockIdx.x * 256 + threadIdx.x;  // < 524288
    int b = eg >> 14;
    int i = ei[eg], j = ej[eg];
    int ri = b * N_ + i, rj = b * N_ + j;

    float4 xi = *(const float4*)(x + ri * 4);
    float4 xj = *(const float4*)(x + rj * 4);
    float xdx = xi.x - xj.x, xdy = xi.y - xj.y, xdz = xi.z - xj.z, xdw = xi.w - xj.w;
    float nsq = xdx * xdx - xdy * xdy - xdz * xdz - xdw * xdw;
    float dsq = xi.x * xj.x - xi.y * xj.y - xi.z * xj.z - xi.w * xj.w;
    float norms = copysignf(log1pf(fabsf(nsq)), nsq);
    float dots  = copysignf(log1pf(fabsf(dsq)), dsq);

    const float4* pt4 = (const float4*)(Ptop + (size_t)ri * 72);
    const float4* pm4 = (const float4*)(Pmid + (size_t)rj * 72);
    const float* w144 = We1 + 144 * 72;
    const float* w145 = We1 + 145 * 72;
    float4* zr = (float4*)(z1 + (size_t)eg * 72);

#pragma unroll
    for (int kc = 0; kc < 18; ++kc) {
        float4 a = pt4[kc];
        float4 bq = pm4[kc];
        float4 wa = *(const float4*)(w144 + 4 * kc);
        float4 wb = *(const float4*)(w145 + 4 * kc);
        float4 r;
        r.x = fmaf(norms, wa.x, fmaf(dots, wb.x, a.x + bq.x));
        r.y = fmaf(norms, wa.y, fmaf(dots, wb.y, a.y + bq.y));
        r.z = fmaf(norms, wa.z, fmaf(dots, wb.z, a.z + bq.z));
        r.w = fmaf(norms, wa.w, fmaf(dots, wb.w, a.w + bq.w));
        zr[kc] = r;
    }
}

// -------------------- channel-strided BN stats --------------------
__global__ __launch_bounds__(256) void k_stats(
    const float* __restrict__ src, float* __restrict__ sPart,
    float* __restrict__ qPart, int iters)
{
    int tid = blockIdx.x * 256 + threadIdx.x;   // < 36864
    float s = 0.f, q = 0.f;
    size_t idx = tid;
    for (int it = 0; it < iters; ++it, idx += NSTAT_T) {
        float v = src[idx];
        s += v;
        q = fmaf(v, v, q);
    }
    sPart[tid] = s;
    qPart[tid] = q;
}

__global__ void k_fin2(const float* __restrict__ sPart, const float* __restrict__ qPart,
                       const float* __restrict__ g, const float* __restrict__ be,
                       float* __restrict__ A, float* __restrict__ Bv, float Minv)
{
    int c = threadIdx.x;
    if (c < 72) {
        float s = 0.f, q = 0.f;
        for (int k = 0; k < 512; ++k) {
            s += sPart[c + 72 * k];
            q += qPart[c + 72 * k];
        }
        float mu = s * Minv;
        float var = q * Minv - mu * mu;
        float inv = rsqrtf(var + EPS_);
        float a = g[c] * inv;
        A[c] = a;
        Bv[c] = be[c] - mu * a;
    }
}

// -------------------- edge pass 2 via MFMA (software-prefetched) --------------------
__global__ __launch_bounds__(256) void k_e2m(
    const float* __restrict__ x,
    const int* __restrict__ ei, const int* __restrict__ ej,
    const float* __restrict__ We2, const float* __restrict__ be2,
    const float* __restrict__ Wm, const float* __restrict__ bm,
    const float* __restrict__ bx1, const float* __restrict__ Wx1,
    const float* __restrict__ Wx2,
    const float* __restrict__ Ae, const float* __restrict__ Be,
    float* mz,                           // z1 in, m out (same region)
    float* __restrict__ magg, float* __restrict__ agg, float* __restrict__ cnt)
{
    __shared__ short WtS[80 * 104];
    __shared__ float lmagg[128 * 73];
    __shared__ float lagg[128 * 5];
    __shared__ float lcnt[128];
    int t = threadIdx.x;
    for (int idx = t; idx < 128 * 73; idx += 256) lmagg[idx] = 0.f;
    for (int idx = t; idx < 128 * 5; idx += 256) lagg[idx] = 0.f;
    if (t < 128) lcnt[t] = 0.f;
    for (int idx = t; idx < 80 * 104; idx += 256) {
        int n = idx / 104, k = idx - n * 104;
        float v = (n < 72 && k < 72) ? We2[k * 72 + n] : 0.f;
        WtS[idx] = f2bf(v);
    }
    __syncthreads();

    int b = blockIdx.x >> 4, chunk = blockIdx.x & 15;
    int base = b * E_ + chunk * 1024;
    int w = t >> 6, l = t & 63, ln = l & 15, g4 = l >> 4;
    float bm0 = bm[0];

    float4 a00 = *(const float4*)(Ae + g4 * 8),      a01 = *(const float4*)(Ae + g4 * 8 + 4);
    float4 b00 = *(const float4*)(Be + g4 * 8),      b01 = *(const float4*)(Be + g4 * 8 + 4);
    float4 a10 = *(const float4*)(Ae + 32 + g4 * 8), a11 = *(const float4*)(Ae + 32 + g4 * 8 + 4);
    float4 b10 = *(const float4*)(Be + 32 + g4 * 8), b11 = *(const float4*)(Be + 32 + g4 * 8 + 4);
    float4 a20, a21, b20, b21;
    if (g4 == 0) {
        a20 = *(const float4*)(Ae + 64); a21 = *(const float4*)(Ae + 68);
        b20 = *(const float4*)(Be + 64); b21 = *(const float4*)(Be + 68);
    } else {
        a20 = make_float4(0, 0, 0, 0); a21 = a20; b20 = a20; b21 = a20;
    }
    float be2v[5], wmv[5], bxv[5], wxv[5];
#pragma unroll
    for (int nt = 0; nt < 5; ++nt) {
        int chan = nt * 16 + ln;
        bool cv = chan < 72;
        be2v[nt] = cv ? be2[chan] : 0.f;
        wmv[nt]  = cv ? Wm[chan]  : 0.f;
        bxv[nt]  = cv ? bx1[chan] : 0.f;
        wxv[nt]  = cv ? Wx2[chan] : 0.f;
    }
    const short8v zero8 = {0, 0, 0, 0, 0, 0, 0, 0};

    // =================== phase A ===================
    float4 c0a, c0b, c1a, c1b, c2a, c2b;
    {
        int es = base + w * 64;
        const float* zrow = mz + (size_t)(es + ln) * 72 + g4 * 8;
        c0a = *(const float4*)(zrow);
        c0b = *(const float4*)(zrow + 4);
        c1a = *(const float4*)(zrow + 32);
        c1b = *(const float4*)(zrow + 36);
        if (g4 == 0) {
            c2a = *(const float4*)(mz + (size_t)(es + ln) * 72 + 64);
            c2b = *(const float4*)(mz + (size_t)(es + ln) * 72 + 68);
        } else { c2a = make_float4(0, 0, 0, 0); c2b = c2a; }
    }
    for (int ts = 0; ts < 16; ++ts) {
        int es = base + w * 64 + (ts >> 2) * 256 + (ts & 3) * 16;
        // prefetch next subtile's z before the compute chain
        float4 n0a, n0b, n1a, n1b, n2a, n2b;
        if (ts < 15) {
            int es2 = base + w * 64 + ((ts + 1) >> 2) * 256 + ((ts + 1) & 3) * 16;
            const float* zrow2 = mz + (size_t)(es2 + ln) * 72 + g4 * 8;
            n0a = *(const float4*)(zrow2);
            n0b = *(const float4*)(zrow2 + 4);
            n1a = *(const float4*)(zrow2 + 32);
            n1b = *(const float4*)(zrow2 + 36);
            if (g4 == 0) {
                n2a = *(const float4*)(mz + (size_t)(es2 + ln) * 72 + 64);
                n2b = *(const float4*)(mz + (size_t)(es2 + ln) * 72 + 68);
            } else { n2a = make_float4(0, 0, 0, 0); n2b = n2a; }
        }

        short8v az0, az1, az2 = zero8;
        az0[0] = f2bf(fmaxf(fmaf(c0a.x, a00.x, b00.x), 0.f));
        az0[1] = f2bf(fmaxf(fmaf(c0a.y, a00.y, b00.y), 0.f));
        az0[2] = f2bf(fmaxf(fmaf(c0a.z, a00.z, b00.z), 0.f));
        az0[3] = f2bf(fmaxf(fmaf(c0a.w, a00.w, b00.w), 0.f));
        az0[4] = f2bf(fmaxf(fmaf(c0b.x, a01.x, b01.x), 0.f));
        az0[5] = f2bf(fmaxf(fmaf(c0b.y, a01.y, b01.y), 0.f));
        az0[6] = f2bf(fmaxf(fmaf(c0b.z, a01.z, b01.z), 0.f));
        az0[7] = f2bf(fmaxf(fmaf(c0b.w, a01.w, b01.w), 0.f));
        az1[0] = f2bf(fmaxf(fmaf(c1a.x, a10.x, b10.x), 0.f));
        az1[1] = f2bf(fmaxf(fmaf(c1a.y, a10.y, b10.y), 0.f));
        az1[2] = f2bf(fmaxf(fmaf(c1a.z, a10.z, b10.z), 0.f));
        az1[3] = f2bf(fmaxf(fmaf(c1a.w, a10.w, b10.w), 0.f));
        az1[4] = f2bf(fmaxf(fmaf(c1b.x, a11.x, b11.x), 0.f));
        az1[5] = f2bf(fmaxf(fmaf(c1b.y, a11.y, b11.y), 0.f));
        az1[6] = f2bf(fmaxf(fmaf(c1b.z, a11.z, b11.z), 0.f));
        az1[7] = f2bf(fmaxf(fmaf(c1b.w, a11.w, b11.w), 0.f));
        if (g4 == 0) {
            az2[0] = f2bf(fmaxf(fmaf(c2a.x, a20.x, b20.x), 0.f));
            az2[1] = f2bf(fmaxf(fmaf(c2a.y, a20.y, b20.y), 0.f));
            az2[2] = f2bf(fmaxf(fmaf(c2a.z, a20.z, b20.z), 0.f));
            az2[3] = f2bf(fmaxf(fmaf(c2a.w, a20.w, b20.w), 0.f));
            az2[4] = f2bf(fmaxf(fmaf(c2b.x, a21.x, b21.x), 0.f));
            az2[5] = f2bf(fmaxf(fmaf(c2b.y, a21.y, b21.y), 0.f));
            az2[6] = f2bf(fmaxf(fmaf(c2b.z, a21.z, b21.z), 0.f));
            az2[7] = f2bf(fmaxf(fmaf(c2b.w, a21.w, b21.w), 0.f));
        }

        f32x4v acc[5];
#pragma unroll
        for (int nt = 0; nt < 5; ++nt) { f32x4v zz = {0.f, 0.f, 0.f, 0.f}; acc[nt] = zz; }
#pragma unroll
        for (int nt = 0; nt < 5; ++nt) {
            int rb = (nt * 16 + ln) * 104 + g4 * 8;
            short8v bw0 = *(const short8v*)&WtS[rb];
            short8v bw1 = *(const short8v*)&WtS[rb + 32];
            short8v bw2 = *(const short8v*)&WtS[rb + 64];
            acc[nt] = __builtin_amdgcn_mfma_f32_16x16x32_bf16(az0, bw0, acc[nt], 0, 0, 0);
            acc[nt] = __builtin_amdgcn_mfma_f32_16x16x32_bf16(az1, bw1, acc[nt], 0, 0, 0);
            acc[nt] = __builtin_amdgcn_mfma_f32_16x16x32_bf16(az2, bw2, acc[nt], 0, 0, 0);
        }

        float mt[5][4];
        float wdot[4] = {bm0, bm0, bm0, bm0};
#pragma unroll
        for (int nt = 0; nt < 5; ++nt) {
#pragma unroll
            for (int r = 0; r < 4; ++r) {
                mt[nt][r] = fmaxf(acc[nt][r] + be2v[nt], 0.f);
                wdot[r] = fmaf(mt[nt][r], wmv[nt], wdot[r]);
            }
        }
#pragma unroll
        for (int r = 0; r < 4; ++r) {
            wdot[r] += __shfl_xor(wdot[r], 1);
            wdot[r] += __shfl_xor(wdot[r], 2);
            wdot[r] += __shfl_xor(wdot[r], 4);
            wdot[r] += __shfl_xor(wdot[r], 8);
            wdot[r] = 1.f / (1.f + expf(-wdot[r]));
        }
#pragma unroll
        for (int nt = 0; nt < 5; ++nt) {
            int chan = nt * 16 + ln;
            if (chan < 72) {
#pragma unroll
                for (int r = 0; r < 4; ++r)
                    mz[(size_t)(es + g4 * 4 + r) * 72 + chan] = mt[nt][r] * wdot[r];
            }
        }
        if (ts < 15) {
            c0a = n0a; c0b = n0b; c1a = n1a; c1b = n1b; c2a = n2a; c2b = n2b;
        }
    }
    __syncthreads();
    for (int idx = t; idx < 80 * 104; idx += 256) {
        int n = idx / 104, k = idx - n * 104;
        float v = (n < 72 && k < 72) ? Wx1[k * 72 + n] : 0.f;
        WtS[idx] = f2bf(v);
    }
    __syncthreads();

    // =================== phase B ===================
    float4 m0a, m0b, m1a, m1b, m2a, m2b;
    {
        int es = base + w * 64;
        const float* mrow = mz + (size_t)(es + ln) * 72 + g4 * 8;
        m0a = *(const float4*)(mrow);
        m0b = *(const float4*)(mrow + 4);
        m1a = *(const float4*)(mrow + 32);
        m1b = *(const float4*)(mrow + 36);
        if (g4 == 0) {
            m2a = *(const float4*)(mz + (size_t)(es + ln) * 72 + 64);
            m2b = *(const float4*)(mz + (size_t)(es + ln) * 72 + 68);
        } else { m2a = make_float4(0, 0, 0, 0); m2b = m2a; }
    }
    for (int ts = 0; ts < 16; ++ts) {
        int es = base + w * 64 + (ts >> 2) * 256 + (ts & 3) * 16;
        float4 n0a, n0b, n1a, n1b, n2a, n2b;
        if (ts < 15) {
            int es2 = base + w * 64 + ((ts + 1) >> 2) * 256 + ((ts + 1) & 3) * 16;
            const float* mrow2 = mz + (size_t)(es2 + ln) * 72 + g4 * 8;
            n0a = *(const float4*)(mrow2);
            n0b = *(const float4*)(mrow2 + 4);
            n1a = *(const float4*)(mrow2 + 32);
            n1b = *(const float4*)(mrow2 + 36);
            if (g4 == 0) {
                n2a = *(const float4*)(mz + (size_t)(es2 + ln) * 72 + 64);
                n2b = *(const float4*)(mz + (size_t)(es2 + ln) * 72 + 68);
            } else { n2a = make_float4(0, 0, 0, 0); n2b = n2a; }
        }

        short8v am0, am1, am2 = zero8;
        am0[0] = f2bf(m0a.x); am0[1] = f2bf(m0a.y); am0[2] = f2bf(m0a.z); am0[3] = f2bf(m0a.w);
        am0[4] = f2bf(m0b.x); am0[5] = f2bf(m0b.y); am0[6] = f2bf(m0b.z); am0[7] = f2bf(m0b.w);
        am1[0] = f2bf(m1a.x); am1[1] = f2bf(m1a.y); am1[2] = f2bf(m1a.z); am1[3] = f2bf(m1a.w);
        am1[4] = f2bf(m1b.x); am1[5] = f2bf(m1b.y); am1[6] = f2bf(m1b.z); am1[7] = f2bf(m1b.w);
        if (g4 == 0) {
            am2[0] = f2bf(m2a.x); am2[1] = f2bf(m2a.y); am2[2] = f2bf(m2a.z); am2[3] = f2bf(m2a.w);
            am2[4] = f2bf(m2b.x); am2[5] = f2bf(m2b.y); am2[6] = f2bf(m2b.z); am2[7] = f2bf(m2b.w);
        }

        f32x4v acc[5];
#pragma unroll
        for (int nt = 0; nt < 5; ++nt) { f32x4v zz = {0.f, 0.f, 0.f, 0.f}; acc[nt] = zz; }
#pragma unroll
        for (int nt = 0; nt < 5; ++nt) {
            int rb = (nt * 16 + ln) * 104 + g4 * 8;
            short8v bw0 = *(const short8v*)&WtS[rb];
            short8v bw1 = *(const short8v*)&WtS[rb + 32];
            short8v bw2 = *(const short8v*)&WtS[rb + 64];
            acc[nt] = __builtin_amdgcn_mfma_f32_16x16x32_bf16(am0, bw0, acc[nt], 0, 0, 0);
            acc[nt] = __builtin_amdgcn_mfma_f32_16x16x32_bf16(am1, bw1, acc[nt], 0, 0, 0);
            acc[nt] = __builtin_amdgcn_mfma_f32_16x16x32_bf16(am2, bw2, acc[nt], 0, 0, 0);
        }

        float ph[4] = {0.f, 0.f, 0.f, 0.f};
#pragma unroll
        for (int nt = 0; nt < 5; ++nt) {
#pragma unroll
            for (int r = 0; r < 4; ++r)
                ph[r] = fmaf(fmaxf(acc[nt][r] + bxv[nt], 0.f), wxv[nt], ph[r]);
        }
#pragma unroll
        for (int r = 0; r < 4; ++r) {
            ph[r] += __shfl_xor(ph[r], 1);
            ph[r] += __shfl_xor(ph[r], 2);
            ph[r] += __shfl_xor(ph[r], 4);
            ph[r] += __shfl_xor(ph[r], 8);
        }
        if (ln == 0) {
#pragma unroll
            for (int r = 0; r < 4; ++r) {
                int eg = es + g4 * 4 + r;
                int ii = ei[eg], jj = ej[eg];
                float4 xi = *(const float4*)(x + (size_t)(b * N_ + ii) * 4);
                float4 xj = *(const float4*)(x + (size_t)(b * N_ + jj) * 4);
                float phx = ph[r];
                float trx = fminf(fmaxf((xi.x - xj.x) * phx, -100.f), 100.f);
                float try_ = fminf(fmaxf((xi.y - xj.y) * phx, -100.f), 100.f);
                float trz = fminf(fmaxf((xi.z - xj.z) * phx, -100.f), 100.f);
                float trw = fminf(fmaxf((xi.w - xj.w) * phx, -100.f), 100.f);
                atomicAdd(&lcnt[ii], 1.f);
                atomicAdd(&lagg[ii * 5 + 0], trx);
                atomicAdd(&lagg[ii * 5 + 1], try_);
                atomicAdd(&lagg[ii * 5 + 2], trz);
                atomicAdd(&lagg[ii * 5 + 3], trw);
            }
        }
        {
            int node = ei[es + ln];
            int kb0 = g4 * 8, kb1 = 32 + g4 * 8;
            int nb73 = node * 73;
            atomicAdd(&lmagg[nb73 + kb0 + 0], m0a.x);
            atomicAdd(&lmagg[nb73 + kb0 + 1], m0a.y);
            atomicAdd(&lmagg[nb73 + kb0 + 2], m0a.z);
            atomicAdd(&lmagg[nb73 + kb0 + 3], m0a.w);
            atomicAdd(&lmagg[nb73 + kb0 + 4], m0b.x);
            atomicAdd(&lmagg[nb73 + kb0 + 5], m0b.y);
            atomicAdd(&lmagg[nb73 + kb0 + 6], m0b.z);
            atomicAdd(&lmagg[nb73 + kb0 + 7], m0b.w);
            atomicAdd(&lmagg[nb73 + kb1 + 0], m1a.x);
            atomicAdd(&lmagg[nb73 + kb1 + 1], m1a.y);
            atomicAdd(&lmagg[nb73 + kb1 + 2], m1a.z);
            atomicAdd(&lmagg[nb73 + kb1 + 3], m1a.w);
            atomicAdd(&lmagg[nb73 + kb1 + 4], m1b.x);
            atomicAdd(&lmagg[nb73 + kb1 + 5], m1b.y);
            atomicAdd(&lmagg[nb73 + kb1 + 6], m1b.z);
            atomicAdd(&lmagg[nb73 + kb1 + 7], m1b.w);
            if (g4 == 0) {
                atomicAdd(&lmagg[nb73 + 64], m2a.x);
                atomicAdd(&lmagg[nb73 + 65], m2a.y);
                atomicAdd(&lmagg[nb73 + 66], m2a.z);
                atomicAdd(&lmagg[nb73 + 67], m2a.w);
                atomicAdd(&lmagg[nb73 + 68], m2b.x);
                atomicAdd(&lmagg[nb73 + 69], m2b.y);
                atomicAdd(&lmagg[nb73 + 70], m2b.z);
                atomicAdd(&lmagg[nb73 + 71], m2b.w);
            }
        }
        if (ts < 15) {
            m0a = n0a; m0b = n0b; m1a = n1a; m1b = n1b; m2a = n2a; m2b = n2b;
        }
    }
    __syncthreads();

    int nb = b * N_;
    for (int idx = t; idx < 128 * 72; idx += 256) {
        int n = idx / 72, c = idx - n * 72;
        float v = lmagg[n * 73 + c];
        if (v != 0.f) atomicAdd(&magg[(size_t)(nb + n) * 72 + c], v);
    }
    for (int idx = t; idx < 128 * 4; idx += 256) {
        int n = idx >> 2, d = idx & 3;
        float v = lagg[n * 5 + d];
        if (v != 0.f) atomicAdd(&agg[(nb + n) * 4 + d], v);
    }
    if (t < 128) {
        float v = lcnt[t];
        if (v != 0.f) atomicAdd(&cnt[nb + t], v);
    }
}

// -------------------- node1 (x8 channel split, q block-uniform) --------------------
__global__ __launch_bounds__(256) void k_node1v3(
    const float* __restrict__ h, const float* __restrict__ magg,
    const float* __restrict__ attr, const float* __restrict__ Wh1,
    const float* __restrict__ bh1, float* __restrict__ zh1)
{
    int blk = blockIdx.x;                  // 128
    int q = blk >> 4;                      // 0..7
    int row = (blk & 15) * 256 + threadIdx.x;   // < 4096
    int c0 = q * 9;
    float acc[9];
#pragma unroll
    for (int c = 0; c < 9; ++c) acc[c] = bh1[c0 + c];

    const float4* h4 = (const float4*)(h + (size_t)row * 72);
    for (int kc = 0; kc < 18; ++kc) {
        float4 a = h4[kc];
        const float* wr = Wh1 + (kc * 4) * 72 + c0;
#pragma unroll
        for (int c = 0; c < 9; ++c)
            acc[c] = fmaf(a.x, wr[c], fmaf(a.y, wr[72 + c], fmaf(a.z, wr[144 + c], fmaf(a.w, wr[216 + c], acc[c]))));
    }
    const float4* mg4 = (const float4*)(magg + (size_t)row * 72);
    for (int kc = 0; kc < 18; ++kc) {
        float4 a = mg4[kc];
        const float* wr = Wh1 + (72 + kc * 4) * 72 + c0;
#pragma unroll
        for (int c = 0; c < 9; ++c)
            acc[c] = fmaf(a.x, wr[c], fmaf(a.y, wr[72 + c], fmaf(a.z, wr[144 + c], fmaf(a.w, wr[216 + c], acc[c]))));
    }
    const float4* at4 = (const float4*)(attr + (size_t)row * 8);
    for (int kc = 0; kc < 2; ++kc) {
        float4 a = at4[kc];
        const float* wr = Wh1 + (144 + kc * 4) * 72 + c0;
#pragma unroll
        for (int c = 0; c < 9; ++c)
            acc[c] = fmaf(a.x, wr[c], fmaf(a.y, wr[72 + c], fmaf(a.z, wr[144 + c], fmaf(a.w, wr[216 + c], acc[c]))));
    }
    float* zr = zh1 + (size_t)row * 72 + c0;
#pragma unroll
    for (int c = 0; c < 9; ++c) zr[c] = acc[c];
}

// -------------------- node2 (x8 channel split, q block-uniform) --------------------
__global__ __launch_bounds__(256) void k_node2v2(
    const float* __restrict__ h, const float* __restrict__ x,
    const float* __restrict__ zh1,
    const float* __restrict__ Ah, const float* __restrict__ Bh,
    const float* __restrict__ Wh2, const float* __restrict__ bh2,
    const float* __restrict__ agg, const float* __restrict__ cnt,
    float* __restrict__ hout, float* __restrict__ xout)
{
    int blk = blockIdx.x;                  // 128
    int q = blk >> 4;                      // 0..7
    int row = (blk & 15) * 256 + threadIdx.x;   // < 4096
    int c0 = q * 9;
    float acc[9];
#pragma unroll
    for (int c = 0; c < 9; ++c) acc[c] = bh2[c0 + c];

    const float4* z4 = (const float4*)(zh1 + (size_t)row * 72);
    for (int kc = 0; kc < 18; ++kc) {
        float4 v = z4[kc];
        int k0 = kc * 4;
        float z0 = fmaxf(fmaf(v.x, Ah[k0],     Bh[k0]),     0.f);
        float z1v = fmaxf(fmaf(v.y, Ah[k0 + 1], Bh[k0 + 1]), 0.f);
        float z2v = fmaxf(fmaf(v.z, Ah[k0 + 2], Bh[k0 + 2]), 0.f);
        float z3v = fmaxf(fmaf(v.w, Ah[k0 + 3], Bh[k0 + 3]), 0.f);
        const float* w0 = Wh2 + k0 * 72 + c0;
#pragma unroll
        for (int c = 0; c < 9; ++c)
            acc[c] = fmaf(z0, w0[c], fmaf(z1v, w0[72 + c], fmaf(z2v, w0[144 + c], fmaf(z3v, w0[216 + c], acc[c]))));
    }
    const float* hr = h + (size_t)row * 72 + c0;
    float* ho = hout + (size_t)row * 72 + c0;
#pragma unroll
    for (int c = 0; c < 9; ++c) ho[c] = hr[c] + acc[c];

    if (q == 0) {
        float inv = 1.f / fmaxf(cnt[row], 1.f);
        float4 xv = *(const float4*)(x + (size_t)row * 4);
        float4 av = *(const float4*)(agg + (size_t)row * 4);
        *(float4*)(xout + (size_t)row * 4) = make_float4(xv.x + av.x * inv, xv.y + av.y * inv,
                                                         xv.z + av.z * inv, xv.w + av.w * inv);
    }
}

extern "C" void kernel_launch(void* const* d_in, const int* in_sizes, int n_in,
                              void* d_out, int out_size, void* d_ws, size_t ws_size,
                              hipStream_t stream) {
    const float* h    = (const float*)d_in[0];
    const float* x    = (const float*)d_in[1];
    const int*   ei   = (const int*)d_in[2];
    const int*   ej   = (const int*)d_in[3];
    const float* attr = (const float*)d_in[4];
    const float* We1  = (const float*)d_in[5];
    const float* ge   = (const float*)d_in[6];
    const float* bee  = (const float*)d_in[7];
    const float* We2  = (const float*)d_in[8];
    const float* be2  = (const float*)d_in[9];
    const float* Wm   = (const float*)d_in[10];
    const float* bm   = (const float*)d_in[11];
    const float* Wx1  = (const float*)d_in[12];
    const float* bx1  = (const float*)d_in[13];
    const float* Wx2  = (const float*)d_in[14];
    const float* Wh1  = (const float*)d_in[15];
    const float* bh1  = (const float*)d_in[16];
    const float* gh   = (const float*)d_in[17];
    const float* beh  = (const float*)d_in[18];
    const float* Wh2  = (const float*)d_in[19];
    const float* bh2  = (const float*)d_in[20];

    float* out  = (float*)d_out;
    float* hout = out + HOUT_OFF;
    float* xout = out + XOUT_OFF;
    float* mz   = out + M_OFF;          // z1 (fp32), then m (fp32), in place
    float* ws   = (float*)d_ws;

    hipMemsetAsync(ws, 0, (size_t)WS_ZERO_END * 4, stream);
    k_nodeproj<<<128, 256, 0, stream>>>(h, We1, ws + WS_ZH1, ws + WS_MAGG);
    k_edge1v3<<<2048, 256, 0, stream>>>(x, ei, ej, ws + WS_ZH1, ws + WS_MAGG, We1, mz);
    k_stats<<<144, 256, 0, stream>>>(mz, ws + WS_MAGG, ws + WS_MAGG + NSTAT_T, 1024);
    k_fin2<<<1, 128, 0, stream>>>(ws + WS_MAGG, ws + WS_MAGG + NSTAT_T, ge, bee,
                                  ws + WS_AE, ws + WS_BE, 1.0f / (float)(B_ * E_));
    hipMemsetAsync(ws + WS_MAGG, 0, (size_t)(B_ * N_ * 72) * 4, stream);
    k_e2m<<<512, 256, 0, stream>>>(x, ei, ej, We2, be2, Wm, bm, bx1, Wx1, Wx2,
                                   ws + WS_AE, ws + WS_BE, mz,
                                   ws + WS_MAGG, ws + WS_AGG, ws + WS_CNT);
    k_node1v3<<<128, 256, 0, stream>>>(h, ws + WS_MAGG, attr, Wh1, bh1, ws + WS_ZH1);
    k_stats<<<144, 256, 0, stream>>>(ws + WS_ZH1, hout, hout + NSTAT_T, 8);
    k_fin2<<<1, 128, 0, stream>>>(hout, hout + NSTAT_T, gh, beh,
                                  ws + WS_AH, ws + WS_BH, 1.0f / 4096.0f);
    k_node2v2<<<128, 256, 0, stream>>>(h, x, ws + WS_ZH1, ws + WS_AH, ws + WS_BH, Wh2, bh2,
                                       ws + WS_AGG, ws + WS_CNT, hout, xout);
}